// Round 1
// baseline (1177.267 us; speedup 1.0000x reference)
//
#include <hip/hip_runtime.h>
#include <hip/hip_bf16.h>
#include <math.h>

// Problem constants (from setup_inputs)
#define B_ROWS 1024
#define NT 8192
#define NS 8192
#define DIM 1024
#define NC 10
#define TEMP 100.0f

// ---------------- reduction helpers ----------------
__device__ inline float wave_max(float v) {
    #pragma unroll
    for (int off = 32; off > 0; off >>= 1)
        v = fmaxf(v, __shfl_down(v, off, 64));
    return v;
}
__device__ inline float wave_sum(float v) {
    #pragma unroll
    for (int off = 32; off > 0; off >>= 1)
        v += __shfl_down(v, off, 64);
    return v;
}

// ---------------- row squared-norms ----------------
__global__ __launch_bounds__(256) void k_row_norms(const float* __restrict__ X,
                                                   float* __restrict__ out) {
    int row = blockIdx.x;
    const float4* xr = (const float4*)(X + (size_t)row * DIM);
    float acc = 0.f;
    // DIM/4 = 256 == blockDim
    float4 v = xr[threadIdx.x];
    acc = v.x * v.x + v.y * v.y + v.z * v.z + v.w * v.w;
    __shared__ float s[4];
    float w = wave_sum(acc);
    int lane = threadIdx.x & 63, wid = threadIdx.x >> 6;
    if (lane == 0) s[wid] = w;
    __syncthreads();
    if (threadIdx.x == 0) out[row] = s[0] + s[1] + s[2] + s[3];
}

// ---------------- tiled fp32 GEMM: C[M,N] = A[M,K] * B[N,K]^T ----------------
#define BM 64
#define BN 64
#define BK 16
__global__ __launch_bounds__(256) void k_gemm_nt(const float* __restrict__ A,
                                                 const float* __restrict__ Bm,
                                                 float* __restrict__ C,
                                                 int M, int N, int K) {
    __shared__ float As[BK][BM];
    __shared__ float Bs[BK][BN];
    int tid = threadIdx.x;
    int tx = tid & 15, ty = tid >> 4;
    int bm = blockIdx.y * BM, bn = blockIdx.x * BN;
    float acc[4][4] = {};
    int lrow = tid >> 2;             // 0..63
    int lk4 = (tid & 3) << 2;        // 0,4,8,12
    const float* aptr = A + (size_t)(bm + lrow) * K + lk4;
    const float* bptr = Bm + (size_t)(bn + lrow) * K + lk4;
    for (int k0 = 0; k0 < K; k0 += BK) {
        float4 av = *(const float4*)(aptr + k0);
        float4 bv = *(const float4*)(bptr + k0);
        __syncthreads();
        As[lk4 + 0][lrow] = av.x; As[lk4 + 1][lrow] = av.y;
        As[lk4 + 2][lrow] = av.z; As[lk4 + 3][lrow] = av.w;
        Bs[lk4 + 0][lrow] = bv.x; Bs[lk4 + 1][lrow] = bv.y;
        Bs[lk4 + 2][lrow] = bv.z; Bs[lk4 + 3][lrow] = bv.w;
        __syncthreads();
        #pragma unroll
        for (int k = 0; k < BK; k++) {
            float4 a = *(const float4*)&As[k][ty << 2];
            float4 b = *(const float4*)&Bs[k][tx << 2];
            float ar[4] = {a.x, a.y, a.z, a.w};
            float br[4] = {b.x, b.y, b.z, b.w};
            #pragma unroll
            for (int i = 0; i < 4; i++)
                #pragma unroll
                for (int j = 0; j < 4; j++)
                    acc[i][j] += ar[i] * br[j];
        }
    }
    #pragma unroll
    for (int i = 0; i < 4; i++) {
        float4 o = make_float4(acc[i][0], acc[i][1], acc[i][2], acc[i][3]);
        *(float4*)(C + (size_t)(bm + (ty << 2) + i) * N + bn + (tx << 2)) = o;
    }
}

// ---------------- tiled fp32 GEMM: C[M,N] = A[M,K] * B[K,N] ----------------
__global__ __launch_bounds__(256) void k_gemm_nn(const float* __restrict__ A,
                                                 const float* __restrict__ Bm,
                                                 float* __restrict__ C,
                                                 int M, int N, int K) {
    __shared__ float As[BK][BM];
    __shared__ float Bs[BK][BN];
    int tid = threadIdx.x;
    int tx = tid & 15, ty = tid >> 4;
    int bm = blockIdx.y * BM, bn = blockIdx.x * BN;
    float acc[4][4] = {};
    int lrow = tid >> 2;             // 0..63 (A tile row)
    int lk4 = (tid & 3) << 2;        // A tile k quad
    int bk = tid >> 4;               // 0..15 (B tile k)
    int bn4 = (tid & 15) << 2;       // B tile col quad
    const float* aptr = A + (size_t)(bm + lrow) * K + lk4;
    const float* bptr = Bm + (size_t)bk * N + bn + bn4;
    for (int k0 = 0; k0 < K; k0 += BK) {
        float4 av = *(const float4*)(aptr + k0);
        float4 bv = *(const float4*)(bptr + (size_t)k0 * N);
        __syncthreads();
        As[lk4 + 0][lrow] = av.x; As[lk4 + 1][lrow] = av.y;
        As[lk4 + 2][lrow] = av.z; As[lk4 + 3][lrow] = av.w;
        *(float4*)&Bs[bk][bn4] = bv;
        __syncthreads();
        #pragma unroll
        for (int k = 0; k < BK; k++) {
            float4 a = *(const float4*)&As[k][ty << 2];
            float4 b = *(const float4*)&Bs[k][tx << 2];
            float ar[4] = {a.x, a.y, a.z, a.w};
            float br[4] = {b.x, b.y, b.z, b.w};
            #pragma unroll
            for (int i = 0; i < 4; i++)
                #pragma unroll
                for (int j = 0; j < 4; j++)
                    acc[i][j] += ar[i] * br[j];
        }
    }
    #pragma unroll
    for (int i = 0; i < 4; i++) {
        float4 o = make_float4(acc[i][0], acc[i][1], acc[i][2], acc[i][3]);
        *(float4*)(C + (size_t)(bm + (ty << 2) + i) * N + bn + (tx << 2)) = o;
    }
}

// ---------------- feature transport softmax (in place on S) ----------------
// S[row][j] holds xf.tf^T dot; replace with softmax_j(-TEMP*sqrt(max(nx+nt-2s,eps)))
__global__ __launch_bounds__(256) void k_feat_softmax(float* __restrict__ S,
                                                      const float* __restrict__ nx,
                                                      const float* __restrict__ nt) {
    int row = blockIdx.x;
    float* sr = S + (size_t)row * NT;
    float nxv = nx[row];
    float vals[NT / 256];
    float lmax = -1e30f;
    #pragma unroll
    for (int u = 0; u < NT / 256; u++) {
        int j = threadIdx.x + u * 256;
        float s = sr[j];
        float sq = nxv + nt[j] - 2.f * s;
        float d = sqrtf(fmaxf(sq, 1e-12f));
        float l = -TEMP * d;
        vals[u] = l;
        lmax = fmaxf(lmax, l);
    }
    __shared__ float sm[4];
    __shared__ float ss[4];
    int lane = threadIdx.x & 63, wid = threadIdx.x >> 6;
    float wm = wave_max(lmax);
    if (lane == 0) sm[wid] = wm;
    __syncthreads();
    float bmax = fmaxf(fmaxf(sm[0], sm[1]), fmaxf(sm[2], sm[3]));
    float lsum = 0.f;
    #pragma unroll
    for (int u = 0; u < NT / 256; u++) {
        float e = __expf(vals[u] - bmax);
        vals[u] = e;
        lsum += e;
    }
    float wsumv = wave_sum(lsum);
    if (lane == 0) ss[wid] = wsumv;
    __syncthreads();
    float bsum = ss[0] + ss[1] + ss[2] + ss[3];
    float inv = 1.0f / bsum;
    #pragma unroll
    for (int u = 0; u < NT / 256; u++) {
        int j = threadIdx.x + u * 256;
        sr[j] = vals[u] * inv;
    }
}

// ---------------- classifier head + softmax over 10 classes ----------------
__global__ __launch_bounds__(64) void k_preds(const float* __restrict__ xsrc,
                                              const float* __restrict__ W,
                                              const float* __restrict__ bias,
                                              float* __restrict__ preds) {
    int row = blockIdx.x;
    const float* xr = xsrc + (size_t)row * DIM;
    float acc[NC] = {};
    #pragma unroll
    for (int kk = 0; kk < DIM / 64; kk++) {
        int k = kk * 64 + threadIdx.x;
        float xv = xr[k];
        #pragma unroll
        for (int c = 0; c < NC; c++) acc[c] += xv * W[k * NC + c];
    }
    #pragma unroll
    for (int c = 0; c < NC; c++) acc[c] = wave_sum(acc[c]);
    if (threadIdx.x == 0) {
        float lo[NC];
        float m = -1e30f;
        #pragma unroll
        for (int c = 0; c < NC; c++) {
            lo[c] = acc[c] + bias[c];
            m = fmaxf(m, lo[c]);
        }
        float s = 0.f;
        #pragma unroll
        for (int c = 0; c < NC; c++) {
            lo[c] = __expf(lo[c] - m);
            s += lo[c];
        }
        float inv = 1.0f / s;
        #pragma unroll
        for (int c = 0; c < NC; c++) preds[(size_t)row * NC + c] = lo[c] * inv;
    }
}

// ---------------- M2T[j][c] = sum_k sld[c][k] * shdl[j][k] ----------------
__global__ __launch_bounds__(256) void k_m2t(const float* __restrict__ sld,
                                             const float* __restrict__ shdl,
                                             float* __restrict__ M2T) {
    int idx = blockIdx.x * blockDim.x + threadIdx.x;
    if (idx >= NS * NC) return;
    int j = idx / NC, c = idx % NC;
    float t = 0.f;
    #pragma unroll
    for (int k = 0; k < NC; k++) t += sld[c * NC + k] * shdl[j * NC + k];
    M2T[idx] = t;
}

// ---------------- label transport softmax fused with y = w_lab @ atl ----------
__global__ __launch_bounds__(256) void k_lab_softmax_y(const float* __restrict__ S,
                                                       const float* __restrict__ nx2,
                                                       const float* __restrict__ ns,
                                                       const float* __restrict__ preds,
                                                       const float* __restrict__ M2T,
                                                       const float* __restrict__ atl,
                                                       float* __restrict__ y) {
    int row = blockIdx.x;
    __shared__ float p[NC];
    __shared__ float sm[4];
    __shared__ float ss[4];
    __shared__ float yred[4][NC];
    if (threadIdx.x < NC) p[threadIdx.x] = preds[(size_t)row * NC + threadIdx.x];
    __syncthreads();
    float pr[NC];
    #pragma unroll
    for (int c = 0; c < NC; c++) pr[c] = p[c];
    const float* sr = S + (size_t)row * NS;
    float nxv = nx2[row];
    float vals[NS / 256];
    float lmax = -1e30f;
    #pragma unroll
    for (int u = 0; u < NS / 256; u++) {
        int j = threadIdx.x + u * 256;
        float s = sr[j];
        float sq = nxv + ns[j] - 2.f * s;
        float d = sqrtf(fmaxf(sq, 1e-12f));
        float lab = 0.f;
        #pragma unroll
        for (int c = 0; c < NC; c++) lab += pr[c] * M2T[(size_t)j * NC + c];
        float l = -TEMP * (d + lab);   // ETA = 1
        vals[u] = l;
        lmax = fmaxf(lmax, l);
    }
    int lane = threadIdx.x & 63, wid = threadIdx.x >> 6;
    float wm = wave_max(lmax);
    if (lane == 0) sm[wid] = wm;
    __syncthreads();
    float bmax = fmaxf(fmaxf(sm[0], sm[1]), fmaxf(sm[2], sm[3]));
    float lsum = 0.f;
    #pragma unroll
    for (int u = 0; u < NS / 256; u++) {
        float e = __expf(vals[u] - bmax);
        vals[u] = e;
        lsum += e;
    }
    float wsv = wave_sum(lsum);
    if (lane == 0) ss[wid] = wsv;
    __syncthreads();
    float bsum = ss[0] + ss[1] + ss[2] + ss[3];
    float inv = 1.0f / bsum;
    float yacc[NC] = {};
    #pragma unroll
    for (int u = 0; u < NS / 256; u++) {
        int j = threadIdx.x + u * 256;
        float w = vals[u] * inv;
        #pragma unroll
        for (int c = 0; c < NC; c++) yacc[c] += w * atl[(size_t)j * NC + c];
    }
    #pragma unroll
    for (int c = 0; c < NC; c++) yacc[c] = wave_sum(yacc[c]);
    if (lane == 0) {
        #pragma unroll
        for (int c = 0; c < NC; c++) yred[wid][c] = yacc[c];
    }
    __syncthreads();
    if (threadIdx.x < NC) {
        int c = threadIdx.x;
        y[(size_t)row * NC + c] = yred[0][c] + yred[1][c] + yred[2][c] + yred[3][c];
    }
}

extern "C" void kernel_launch(void* const* d_in, const int* in_sizes, int n_in,
                              void* d_out, int out_size, void* d_ws, size_t ws_size,
                              hipStream_t stream) {
    const float* x    = (const float*)d_in[0];   // [1024, 32, 32]
    const float* tf   = (const float*)d_in[1];   // [8192, 1024]
    const float* asf  = (const float*)d_in[2];   // [8192, 1024]
    const float* sf   = (const float*)d_in[3];   // [8192, 1024]
    const float* shdl = (const float*)d_in[4];   // [8192, 10]
    const float* atl  = (const float*)d_in[5];   // [8192, 10]
    const float* sld  = (const float*)d_in[6];   // [10, 10]
    const float* W    = (const float*)d_in[7];   // [1024, 10]
    const float* bias = (const float*)d_in[8];   // [10]
    float* y = (float*)d_out;                    // [1024, 10] fp32

    float* ws = (float*)d_ws;
    // workspace layout (floats)
    float* S     = ws;                            // 1024*8192 = 8388608 (reused)
    float* xsrc  = ws + 8388608;                  // 1024*1024
    float* nt_   = ws + 8388608 + 1048576;        // 8192
    float* ns_   = nt_ + NT;                      // 8192
    float* nx_   = ns_ + NS;                      // 1024
    float* nx2_  = nx_ + B_ROWS;                  // 1024
    float* preds = nx2_ + B_ROWS;                 // 10240
    float* M2T   = preds + B_ROWS * NC;           // 81920

    // row norms
    k_row_norms<<<NT, 256, 0, stream>>>(tf, nt_);
    k_row_norms<<<NS, 256, 0, stream>>>(sf, ns_);
    k_row_norms<<<B_ROWS, 256, 0, stream>>>(x, nx_);
    // M2T (independent)
    k_m2t<<<(NS * NC + 255) / 256, 256, 0, stream>>>(sld, shdl, M2T);

    // S1 = xf @ tf^T
    {
        dim3 g(NT / BN, B_ROWS / BM);
        k_gemm_nt<<<g, 256, 0, stream>>>(x, tf, S, B_ROWS, NT, DIM);
    }
    // softmax over rows -> w_feat (in place)
    k_feat_softmax<<<B_ROWS, 256, 0, stream>>>(S, nx_, nt_);
    // x_src = w_feat @ asf
    {
        dim3 g(DIM / BN, B_ROWS / BM);
        k_gemm_nn<<<g, 256, 0, stream>>>(S, asf, xsrc, B_ROWS, DIM, NT);
    }
    // ||x_src||^2 and preds
    k_row_norms<<<B_ROWS, 256, 0, stream>>>(xsrc, nx2_);
    k_preds<<<B_ROWS, 64, 0, stream>>>(xsrc, W, bias, preds);
    // S3 = x_src @ sf^T (overwrites w_feat)
    {
        dim3 g(NS / BN, B_ROWS / BM);
        k_gemm_nt<<<g, 256, 0, stream>>>(xsrc, sf, S, B_ROWS, NS, DIM);
    }
    // label softmax + y
    k_lab_softmax_y<<<B_ROWS, 256, 0, stream>>>(S, nx2_, ns_, preds, M2T, atl, y);
}

// Round 3
// 449.410 us; speedup vs baseline: 2.6196x; 2.6196x over previous
//
#include <hip/hip_runtime.h>
#include <hip/hip_bf16.h>
#include <math.h>

#define B_ROWS 1024
#define NT 8192
#define NS 8192
#define DIM 1024
#define NC 10
#define TEMP 100.0f

typedef __bf16 bf16x8 __attribute__((ext_vector_type(8)));
typedef __bf16 bf16x4 __attribute__((ext_vector_type(4)));
typedef float f32x4 __attribute__((ext_vector_type(4)));

#define GLOAD_LDS(g, l) \
    __builtin_amdgcn_global_load_lds((__attribute__((address_space(1))) void*)(g), \
                                     (__attribute__((address_space(3))) void*)(l), 16, 0, 0)

__device__ inline __bf16 split_hi(float v) { return (__bf16)v; }
__device__ inline __bf16 split_lo(float v) {
    __bf16 h = (__bf16)v;
    return (__bf16)(v - (float)h);
}

// ---------------- reduction helpers ----------------
__device__ inline float wave_max(float v) {
    #pragma unroll
    for (int off = 32; off > 0; off >>= 1)
        v = fmaxf(v, __shfl_down(v, off, 64));
    return v;
}
__device__ inline float wave_sum(float v) {
    #pragma unroll
    for (int off = 32; off > 0; off >>= 1)
        v += __shfl_down(v, off, 64);
    return v;
}

// ---------------- row squared-norms (rows of length 1024) ----------------
__global__ __launch_bounds__(256) void k_row_norms(const float* __restrict__ X,
                                                   float* __restrict__ out) {
    int row = blockIdx.x;
    const float4* xr = (const float4*)(X + (size_t)row * DIM);
    float4 v = xr[threadIdx.x];
    float acc = v.x * v.x + v.y * v.y + v.z * v.z + v.w * v.w;
    __shared__ float s[4];
    float w = wave_sum(acc);
    int lane = threadIdx.x & 63, wid = threadIdx.x >> 6;
    if (lane == 0) s[wid] = w;
    __syncthreads();
    if (threadIdx.x == 0) out[row] = s[0] + s[1] + s[2] + s[3];
}

// ---------------- fp32 -> bf16 hi/lo split, row pitch 2*1024 ----------------
__global__ __launch_bounds__(256) void k_conv2(const float* __restrict__ X,
                                               __bf16* __restrict__ X2) {
    int row = blockIdx.x;
    int c = threadIdx.x * 4;
    float4 v = *(const float4*)(X + (size_t)row * DIM + c);
    bf16x4 h, l;
    h[0] = split_hi(v.x); l[0] = split_lo(v.x);
    h[1] = split_hi(v.y); l[1] = split_lo(v.y);
    h[2] = split_hi(v.z); l[2] = split_lo(v.z);
    h[3] = split_hi(v.w); l[3] = split_lo(v.w);
    *(bf16x4*)(X2 + (size_t)row * 2048 + c) = h;
    *(bf16x4*)(X2 + (size_t)row * 2048 + 1024 + c) = l;
}

// ---------------- asf [8192][1024] -> transposed hi/lo split [1024][2*8192] ----
__global__ __launch_bounds__(256) void k_conv2t(const float* __restrict__ X,
                                                __bf16* __restrict__ XT2) {
    __shared__ float t[64][65];
    int k0 = blockIdx.x * 64;  // source row block (k dim, 8192)
    int n0 = blockIdx.y * 64;  // source col block (n dim, 1024)
    int tid = threadIdx.x;
    int tr = tid >> 4;          // 0..15
    int tc = (tid & 15) * 4;    // 0..60
    #pragma unroll
    for (int i = 0; i < 4; i++) {
        int r = tr + i * 16;
        float4 v = *(const float4*)(X + (size_t)(k0 + r) * 1024 + n0 + tc);
        t[r][tc] = v.x; t[r][tc + 1] = v.y; t[r][tc + 2] = v.z; t[r][tc + 3] = v.w;
    }
    __syncthreads();
    #pragma unroll
    for (int i = 0; i < 4; i++) {
        int n = tr + i * 16;   // output row (n), local
        bf16x4 h, l;
        #pragma unroll
        for (int e = 0; e < 4; e++) {
            float v = t[tc + e][n];
            h[e] = split_hi(v);
            l[e] = split_lo(v);
        }
        size_t base = (size_t)(n0 + n) * 16384 + k0 + tc;
        *(bf16x4*)(XT2 + base) = h;
        *(bf16x4*)(XT2 + base + 8192) = l;
    }
}

// ---------------- 3-term split-bf16 MFMA GEMM: C = A*B^T ----------------
// A2 [M][2K] bf16 (hi|lo), B2 [N][2K] bf16 (hi|lo), C fp32 [M][N] (+z*M*N)
// 128x128 tile, BK=32, split-K via blockIdx.z
__global__ __launch_bounds__(256) void k_gemm3(const __bf16* __restrict__ A2,
                                               const __bf16* __restrict__ B2,
                                               float* __restrict__ C,
                                               int M, int N, int K, int ksplit) {
    __shared__ unsigned short AhS[4096], AlS[4096], BhS[4096], BlS[4096]; // 128x32 each
    int tid = threadIdx.x;
    int wid = tid >> 6, lane = tid & 63;
    int wm = (wid >> 1) * 64, wn = (wid & 1) * 64;
    int bm = blockIdx.y * 128, bn = blockIdx.x * 128;
    size_t K2 = 2 * (size_t)K;
    int k_begin = blockIdx.z * ksplit;
    int nsteps = ksplit >> 5;

    f32x4 acc[4][4];
    #pragma unroll
    for (int i = 0; i < 4; i++)
        #pragma unroll
        for (int j = 0; j < 4; j++) acc[i][j] = (f32x4){0.f, 0.f, 0.f, 0.f};

    // staging mapping: thread -> (row, swizzled k-chunk)
    int sr = tid >> 2;
    int skc = (tid & 3) ^ (sr & 3);
    const __bf16* gA0 = A2 + (size_t)(bm + sr) * K2 + k_begin + skc * 8;
    const __bf16* gA1 = A2 + (size_t)(bm + sr + 64) * K2 + k_begin + skc * 8;
    const __bf16* gB0 = B2 + (size_t)(bn + sr) * K2 + k_begin + skc * 8;
    const __bf16* gB1 = B2 + (size_t)(bn + sr + 64) * K2 + k_begin + skc * 8;

    // fragment read offsets (elements), swizzle-compensated
    int ra = lane & 15, q = lane >> 4;
    int fcol = ((q ^ (ra & 3)) * 8);
    int aoff[4], boff[4];
    #pragma unroll
    for (int i = 0; i < 4; i++) {
        aoff[i] = (wm + i * 16 + ra) * 32 + fcol;
        boff[i] = (wn + i * 16 + ra) * 32 + fcol;
    }
    const __bf16* AhE = (const __bf16*)AhS;
    const __bf16* AlE = (const __bf16*)AlS;
    const __bf16* BhE = (const __bf16*)BhS;
    const __bf16* BlE = (const __bf16*)BlS;
    char* AhB = (char*)AhS; char* AlB = (char*)AlS;
    char* BhB = (char*)BhS; char* BlB = (char*)BlS;
    int lb0 = wid * 1024, lb1 = 4096 + wid * 1024;

    for (int ks = 0; ks < nsteps; ks++) {
        __syncthreads();
        GLOAD_LDS(gA0, AhB + lb0);
        GLOAD_LDS(gA1, AhB + lb1);
        GLOAD_LDS(gA0 + K, AlB + lb0);
        GLOAD_LDS(gA1 + K, AlB + lb1);
        GLOAD_LDS(gB0, BhB + lb0);
        GLOAD_LDS(gB1, BhB + lb1);
        GLOAD_LDS(gB0 + K, BlB + lb0);
        GLOAD_LDS(gB1 + K, BlB + lb1);
        gA0 += 32; gA1 += 32; gB0 += 32; gB1 += 32;
        __syncthreads();

        bf16x8 ah[4], al[4];
        #pragma unroll
        for (int mi = 0; mi < 4; mi++) {
            ah[mi] = *(const bf16x8*)(AhE + aoff[mi]);
            al[mi] = *(const bf16x8*)(AlE + aoff[mi]);
        }
        #pragma unroll
        for (int ni = 0; ni < 4; ni++) {
            bf16x8 bh = *(const bf16x8*)(BhE + boff[ni]);
            bf16x8 bl = *(const bf16x8*)(BlE + boff[ni]);
            #pragma unroll
            for (int mi = 0; mi < 4; mi++) {
                acc[mi][ni] = __builtin_amdgcn_mfma_f32_16x16x32_bf16(ah[mi], bh, acc[mi][ni], 0, 0, 0);
                acc[mi][ni] = __builtin_amdgcn_mfma_f32_16x16x32_bf16(ah[mi], bl, acc[mi][ni], 0, 0, 0);
                acc[mi][ni] = __builtin_amdgcn_mfma_f32_16x16x32_bf16(al[mi], bh, acc[mi][ni], 0, 0, 0);
            }
        }
    }

    float* Cb = C + (size_t)blockIdx.z * M * N;
    #pragma unroll
    for (int mi = 0; mi < 4; mi++) {
        #pragma unroll
        for (int ni = 0; ni < 4; ni++) {
            int r0 = bm + wm + mi * 16 + q * 4;
            int c0 = bn + wn + ni * 16 + ra;
            Cb[(size_t)(r0 + 0) * N + c0] = acc[mi][ni][0];
            Cb[(size_t)(r0 + 1) * N + c0] = acc[mi][ni][1];
            Cb[(size_t)(r0 + 2) * N + c0] = acc[mi][ni][2];
            Cb[(size_t)(r0 + 3) * N + c0] = acc[mi][ni][3];
        }
    }
}

// ---------------- reduce 4 split-K partials ----------------
__global__ __launch_bounds__(256) void k_reduce4(const float4* __restrict__ p,
                                                 float4* __restrict__ out) {
    int idx = blockIdx.x * 256 + threadIdx.x;   // 262144 float4 per plane
    float4 a = p[idx], b = p[idx + 262144], c = p[idx + 524288], d = p[idx + 786432];
    out[idx] = make_float4(a.x + b.x + c.x + d.x, a.y + b.y + c.y + d.y,
                           a.z + b.z + c.z + d.z, a.w + b.w + c.w + d.w);
}

// ---------------- feature softmax -> split-bf16 w (hi|lo, pitch 16384) --------
__global__ __launch_bounds__(256) void k_softmax_w2(const float* __restrict__ S,
                                                    const float* __restrict__ nx,
                                                    const float* __restrict__ nt,
                                                    __bf16* __restrict__ w2) {
    int row = blockIdx.x;
    const float* sr = S + (size_t)row * NT;
    float nxv = nx[row];
    float vals[NT / 256];
    float lmax = -1e30f;
    #pragma unroll
    for (int u = 0; u < NT / 256; u++) {
        int j = threadIdx.x + u * 256;
        float s = sr[j];
        float sq = nxv + nt[j] - 2.f * s;
        float d = sqrtf(fmaxf(sq, 1e-12f));
        float l = -TEMP * d;
        vals[u] = l;
        lmax = fmaxf(lmax, l);
    }
    __shared__ float sm[4];
    __shared__ float ss[4];
    int lane = threadIdx.x & 63, wid = threadIdx.x >> 6;
    float wm = wave_max(lmax);
    if (lane == 0) sm[wid] = wm;
    __syncthreads();
    float bmax = fmaxf(fmaxf(sm[0], sm[1]), fmaxf(sm[2], sm[3]));
    float lsum = 0.f;
    #pragma unroll
    for (int u = 0; u < NT / 256; u++) {
        float e = __expf(vals[u] - bmax);
        vals[u] = e;
        lsum += e;
    }
    float wsumv = wave_sum(lsum);
    if (lane == 0) ss[wid] = wsumv;
    __syncthreads();
    float bsum = ss[0] + ss[1] + ss[2] + ss[3];
    float inv = 1.0f / bsum;
    __bf16* wr = w2 + (size_t)row * 16384;
    #pragma unroll
    for (int u = 0; u < NT / 256; u++) {
        int j = threadIdx.x + u * 256;
        float w = vals[u] * inv;
        wr[j] = split_hi(w);
        wr[8192 + j] = split_lo(w);
    }
}

// ---------------- classifier head + softmax over 10 classes ----------------
__global__ __launch_bounds__(64) void k_preds(const float* __restrict__ xsrc,
                                              const float* __restrict__ W,
                                              const float* __restrict__ bias,
                                              float* __restrict__ preds) {
    int row = blockIdx.x;
    const float* xr = xsrc + (size_t)row * DIM;
    float acc[NC] = {};
    #pragma unroll
    for (int kk = 0; kk < DIM / 64; kk++) {
        int k = kk * 64 + threadIdx.x;
        float xv = xr[k];
        #pragma unroll
        for (int c = 0; c < NC; c++) acc[c] += xv * W[k * NC + c];
    }
    #pragma unroll
    for (int c = 0; c < NC; c++) acc[c] = wave_sum(acc[c]);
    if (threadIdx.x == 0) {
        float lo[NC];
        float m = -1e30f;
        #pragma unroll
        for (int c = 0; c < NC; c++) {
            lo[c] = acc[c] + bias[c];
            m = fmaxf(m, lo[c]);
        }
        float s = 0.f;
        #pragma unroll
        for (int c = 0; c < NC; c++) {
            lo[c] = __expf(lo[c] - m);
            s += lo[c];
        }
        float inv = 1.0f / s;
        #pragma unroll
        for (int c = 0; c < NC; c++) preds[(size_t)row * NC + c] = lo[c] * inv;
    }
}

// ---------------- M2T[j][c] = sum_k sld[c][k] * shdl[j][k] ----------------
__global__ __launch_bounds__(256) void k_m2t(const float* __restrict__ sld,
                                             const float* __restrict__ shdl,
                                             float* __restrict__ M2T) {
    int idx = blockIdx.x * blockDim.x + threadIdx.x;
    if (idx >= NS * NC) return;
    int j = idx / NC, c = idx % NC;
    float t = 0.f;
    #pragma unroll
    for (int k = 0; k < NC; k++) t += sld[c * NC + k] * shdl[j * NC + k];
    M2T[idx] = t;
}

// ---------------- label transport softmax fused with y = w_lab @ atl ----------
__global__ __launch_bounds__(256) void k_lab_softmax_y(const float* __restrict__ S,
                                                       const float* __restrict__ nx2,
                                                       const float* __restrict__ ns,
                                                       const float* __restrict__ preds,
                                                       const float* __restrict__ M2T,
                                                       const float* __restrict__ atl,
                                                       float* __restrict__ y) {
    int row = blockIdx.x;
    __shared__ float p[NC];
    __shared__ float sm[4];
    __shared__ float ss[4];
    __shared__ float yred[4][NC];
    if (threadIdx.x < NC) p[threadIdx.x] = preds[(size_t)row * NC + threadIdx.x];
    __syncthreads();
    float pr[NC];
    #pragma unroll
    for (int c = 0; c < NC; c++) pr[c] = p[c];
    const float* sr = S + (size_t)row * NS;
    float nxv = nx2[row];
    float vals[NS / 256];
    float lmax = -1e30f;
    #pragma unroll
    for (int u = 0; u < NS / 256; u++) {
        int j = threadIdx.x + u * 256;
        float s = sr[j];
        float sq = nxv + ns[j] - 2.f * s;
        float d = sqrtf(fmaxf(sq, 1e-12f));
        float lab = 0.f;
        #pragma unroll
        for (int c = 0; c < NC; c++) lab += pr[c] * M2T[(size_t)j * NC + c];
        float l = -TEMP * (d + lab);   // ETA = 1
        vals[u] = l;
        lmax = fmaxf(lmax, l);
    }
    int lane = threadIdx.x & 63, wid = threadIdx.x >> 6;
    float wm = wave_max(lmax);
    if (lane == 0) sm[wid] = wm;
    __syncthreads();
    float bmax = fmaxf(fmaxf(sm[0], sm[1]), fmaxf(sm[2], sm[3]));
    float lsum = 0.f;
    #pragma unroll
    for (int u = 0; u < NS / 256; u++) {
        float e = __expf(vals[u] - bmax);
        vals[u] = e;
        lsum += e;
    }
    float wsv = wave_sum(lsum);
    if (lane == 0) ss[wid] = wsv;
    __syncthreads();
    float bsum = ss[0] + ss[1] + ss[2] + ss[3];
    float inv = 1.0f / bsum;
    float yacc[NC] = {};
    #pragma unroll
    for (int u = 0; u < NS / 256; u++) {
        int j = threadIdx.x + u * 256;
        float w = vals[u] * inv;
        #pragma unroll
        for (int c = 0; c < NC; c++) yacc[c] += w * atl[(size_t)j * NC + c];
    }
    #pragma unroll
    for (int c = 0; c < NC; c++) yacc[c] = wave_sum(yacc[c]);
    if (lane == 0) {
        #pragma unroll
        for (int c = 0; c < NC; c++) yred[wid][c] = yacc[c];
    }
    __syncthreads();
    if (threadIdx.x < NC) {
        int c = threadIdx.x;
        y[(size_t)row * NC + c] = yred[0][c] + yred[1][c] + yred[2][c] + yred[3][c];
    }
}

extern "C" void kernel_launch(void* const* d_in, const int* in_sizes, int n_in,
                              void* d_out, int out_size, void* d_ws, size_t ws_size,
                              hipStream_t stream) {
    const float* x    = (const float*)d_in[0];   // [1024, 32, 32]
    const float* tf   = (const float*)d_in[1];   // [8192, 1024]
    const float* asf  = (const float*)d_in[2];   // [8192, 1024]
    const float* sf   = (const float*)d_in[3];   // [8192, 1024]
    const float* shdl = (const float*)d_in[4];   // [8192, 10]
    const float* atl  = (const float*)d_in[5];   // [8192, 10]
    const float* sld  = (const float*)d_in[6];   // [10, 10]
    const float* W    = (const float*)d_in[7];   // [1024, 10]
    const float* bias = (const float*)d_in[8];   // [10]
    float* y = (float*)d_out;                    // [1024, 10]

    char* wsb = (char*)d_ws;
    float*  S     = (float*)(wsb);                          // 32 MiB; later aliased by asfT2
    __bf16* asfT2 = (__bf16*)S;                             // [1024][16384] (after softmax)
    float*  BIG1  = (float*)(wsb + (32u << 20));            // 32 MiB: tf2 -> partials -> sf2
    __bf16* tf2   = (__bf16*)BIG1;
    float*  parts = BIG1;
    __bf16* sf2   = (__bf16*)BIG1;
    __bf16* w2    = (__bf16*)(wsb + (64u << 20));           // 32 MiB
    __bf16* x2    = (__bf16*)(wsb + (96u << 20));           // 4 MiB
    __bf16* xsrc2 = (__bf16*)(wsb + (100u << 20));          // 4 MiB
    float*  xsrc  = (float*)(wsb + (104u << 20));           // 4 MiB
    float*  nt_   = (float*)(wsb + (108u << 20));
    float*  ns_   = nt_ + NT;
    float*  nx_   = ns_ + NS;
    float*  nx2_  = nx_ + B_ROWS;
    float*  preds = nx2_ + B_ROWS;
    float*  M2T   = preds + B_ROWS * NC;

    // conversions + norms + label-cost matrix
    k_conv2<<<B_ROWS, 256, 0, stream>>>(x, x2);
    k_conv2<<<NT, 256, 0, stream>>>(tf, tf2);
    k_row_norms<<<NT, 256, 0, stream>>>(tf, nt_);
    k_row_norms<<<NS, 256, 0, stream>>>(sf, ns_);
    k_row_norms<<<B_ROWS, 256, 0, stream>>>(x, nx_);
    k_m2t<<<(NS * NC + 255) / 256, 256, 0, stream>>>(sld, shdl, M2T);

    // G1: S = x @ tf^T   (M=1024, N=8192, K=1024)
    {
        dim3 g(NT / 128, B_ROWS / 128, 1);
        k_gemm3<<<g, 256, 0, stream>>>(x2, tf2, S, B_ROWS, NT, DIM, DIM);
    }
    // w_feat softmax -> split-bf16 w2
    k_softmax_w2<<<B_ROWS, 256, 0, stream>>>(S, nx_, nt_, w2);
    // asf transpose+split into S region (S is dead now)
    {
        dim3 g(NT / 64, DIM / 64);
        k_conv2t<<<g, 256, 0, stream>>>(asf, asfT2);
    }
    // G2: parts[z] = w2 @ asfT2^T  (M=1024, N=1024, K=8192, split-K x4)
    {
        dim3 g(DIM / 128, B_ROWS / 128, 4);
        k_gemm3<<<g, 256, 0, stream>>>(w2, asfT2, parts, B_ROWS, DIM, NT, NT / 4);
    }
    k_reduce4<<<1024, 256, 0, stream>>>((const float4*)parts, (float4*)xsrc);

    k_row_norms<<<B_ROWS, 256, 0, stream>>>(xsrc, nx2_);
    k_preds<<<B_ROWS, 64, 0, stream>>>(xsrc, W, bias, preds);
    k_conv2<<<B_ROWS, 256, 0, stream>>>(xsrc, xsrc2);
    k_conv2<<<NS, 256, 0, stream>>>(sf, sf2);   // overwrites parts (dead)

    // G3: S = xsrc @ sf^T  (M=1024, N=8192, K=1024)
    {
        dim3 g(NS / 128, B_ROWS / 128, 1);
        k_gemm3<<<g, 256, 0, stream>>>(xsrc2, sf2, S, B_ROWS, NS, DIM, DIM);
    }
    // label softmax + y
    k_lab_softmax_y<<<B_ROWS, 256, 0, stream>>>(S, nx2_, ns_, preds, M2T, atl, y);
}

// Round 4
// 380.148 us; speedup vs baseline: 3.0969x; 1.1822x over previous
//
#include <hip/hip_runtime.h>
#include <hip/hip_bf16.h>
#include <math.h>

#define B_ROWS 1024
#define NT 8192
#define NS 8192
#define DIM 1024
#define NC 10
#define TEMP 100.0f

typedef __bf16 bf16x8 __attribute__((ext_vector_type(8)));
typedef __bf16 bf16x4 __attribute__((ext_vector_type(4)));
typedef float f32x4 __attribute__((ext_vector_type(4)));

#define GLOAD_LDS(g, l) \
    __builtin_amdgcn_global_load_lds((__attribute__((address_space(1))) void*)(g), \
                                     (__attribute__((address_space(3))) void*)(l), 16, 0, 0)

__device__ inline __bf16 split_hi(float v) { return (__bf16)v; }
__device__ inline __bf16 split_lo(float v) {
    __bf16 h = (__bf16)v;
    return (__bf16)(v - (float)h);
}

// ---------------- reduction helpers ----------------
__device__ inline float wave_max(float v) {
    #pragma unroll
    for (int off = 32; off > 0; off >>= 1)
        v = fmaxf(v, __shfl_down(v, off, 64));
    return v;
}
__device__ inline float wave_sum(float v) {
    #pragma unroll
    for (int off = 32; off > 0; off >>= 1)
        v += __shfl_down(v, off, 64);
    return v;
}

// ---------------- fused fp32->bf16 hi/lo split + row norm (rows of 1024) -----
__global__ __launch_bounds__(256) void k_conv_norm(const float* __restrict__ X,
                                                   __bf16* __restrict__ X2,
                                                   float* __restrict__ norms) {
    int row = blockIdx.x;
    int c = threadIdx.x * 4;
    float4 v = *(const float4*)(X + (size_t)row * DIM + c);
    bf16x4 h, l;
    h[0] = split_hi(v.x); l[0] = split_lo(v.x);
    h[1] = split_hi(v.y); l[1] = split_lo(v.y);
    h[2] = split_hi(v.z); l[2] = split_lo(v.z);
    h[3] = split_hi(v.w); l[3] = split_lo(v.w);
    *(bf16x4*)(X2 + (size_t)row * 2048 + c) = h;
    *(bf16x4*)(X2 + (size_t)row * 2048 + 1024 + c) = l;
    float acc = v.x * v.x + v.y * v.y + v.z * v.z + v.w * v.w;
    __shared__ float s[4];
    float w = wave_sum(acc);
    int lane = threadIdx.x & 63, wid = threadIdx.x >> 6;
    if (lane == 0) s[wid] = w;
    __syncthreads();
    if (threadIdx.x == 0) norms[row] = s[0] + s[1] + s[2] + s[3];
}

// ---------------- asf [8192][1024] -> transposed hi/lo split [1024][2*8192] ----
__global__ __launch_bounds__(256) void k_conv2t(const float* __restrict__ X,
                                                __bf16* __restrict__ XT2) {
    __shared__ float t[64][65];
    int k0 = blockIdx.x * 64;  // source row block (k dim, 8192)
    int n0 = blockIdx.y * 64;  // source col block (n dim, 1024)
    int tid = threadIdx.x;
    int tr = tid >> 4;          // 0..15
    int tc = (tid & 15) * 4;    // 0..60
    #pragma unroll
    for (int i = 0; i < 4; i++) {
        int r = tr + i * 16;
        float4 v = *(const float4*)(X + (size_t)(k0 + r) * 1024 + n0 + tc);
        t[r][tc] = v.x; t[r][tc + 1] = v.y; t[r][tc + 2] = v.z; t[r][tc + 3] = v.w;
    }
    __syncthreads();
    #pragma unroll
    for (int i = 0; i < 4; i++) {
        int n = tr + i * 16;   // output row (n), local
        bf16x4 h, l;
        #pragma unroll
        for (int e = 0; e < 4; e++) {
            float v = t[tc + e][n];
            h[e] = split_hi(v);
            l[e] = split_lo(v);
        }
        size_t base = (size_t)(n0 + n) * 16384 + k0 + tc;
        *(bf16x4*)(XT2 + base) = h;
        *(bf16x4*)(XT2 + base + 8192) = l;
    }
}

// ---------------- 3-term split-bf16 MFMA GEMM: C = A*B^T ----------------
// A2 [M][2K] bf16 (hi|lo), B2 [N][2K] bf16 (hi|lo), C fp32 [M][N] (+z*M*N)
// 128x128 tile, BK=64, split-K via blockIdx.z
// LDS row = 64 bf16 = 128 B = full bank period; chunk XOR (row&7) -> conflict-free
__global__ __launch_bounds__(256) void k_gemm3(const __bf16* __restrict__ A2,
                                               const __bf16* __restrict__ B2,
                                               float* __restrict__ C,
                                               int M, int N, int K, int ksplit) {
    __shared__ unsigned short AhS[8192], AlS[8192], BhS[8192], BlS[8192]; // 128x64 each
    int tid = threadIdx.x;
    int wid = tid >> 6, lane = tid & 63;
    int wm = (wid >> 1) * 64, wn = (wid & 1) * 64;
    int bm = blockIdx.y * 128, bn = blockIdx.x * 128;
    size_t K2 = 2 * (size_t)K;
    int k_begin = blockIdx.z * ksplit;
    int nsteps = ksplit >> 6;

    f32x4 acc[4][4];
    #pragma unroll
    for (int i = 0; i < 4; i++)
        #pragma unroll
        for (int j = 0; j < 4; j++) acc[i][j] = (f32x4){0.f, 0.f, 0.f, 0.f};

    // staging: wave wid covers rows [wid*32, wid*32+32), 4 glds passes of 8 rows
    int r_in = lane >> 3;                    // 0..7 row within 8-row pass
    int cgo = ((lane & 7) ^ r_in) * 8;       // swizzled chunk (element offset)
    const __bf16* gA = A2 + (size_t)(bm + wid * 32 + r_in) * K2 + k_begin + cgo;
    const __bf16* gB = B2 + (size_t)(bn + wid * 32 + r_in) * K2 + k_begin + cgo;
    char* AhB = (char*)AhS; char* AlB = (char*)AlS;
    char* BhB = (char*)BhS; char* BlB = (char*)BlS;
    int lbw = wid * 4096;
    size_t row8 = 8 * K2;

    // fragment read offsets (elements), swizzle-compensated
    int ra = lane & 15, q = lane >> 4;
    int aoff[4][2], boff[4][2];
    #pragma unroll
    for (int i = 0; i < 4; i++) {
        #pragma unroll
        for (int kh = 0; kh < 2; kh++) {
            int chunk = ((kh << 2) | q) ^ (ra & 7);
            aoff[i][kh] = (wm + i * 16 + ra) * 64 + chunk * 8;
            boff[i][kh] = (wn + i * 16 + ra) * 64 + chunk * 8;
        }
    }
    const __bf16* AhE = (const __bf16*)AhS;
    const __bf16* AlE = (const __bf16*)AlS;
    const __bf16* BhE = (const __bf16*)BhS;
    const __bf16* BlE = (const __bf16*)BlS;

    for (int ks = 0; ks < nsteps; ks++) {
        __syncthreads();
        #pragma unroll
        for (int p = 0; p < 4; p++) {
            size_t go = p * row8;
            int lo = lbw + p * 1024;
            GLOAD_LDS(gA + go, AhB + lo);
            GLOAD_LDS(gA + go + K, AlB + lo);
            GLOAD_LDS(gB + go, BhB + lo);
            GLOAD_LDS(gB + go + K, BlB + lo);
        }
        gA += 64; gB += 64;
        __syncthreads();

        #pragma unroll
        for (int kh = 0; kh < 2; kh++) {
            bf16x8 ah[4], al[4];
            #pragma unroll
            for (int mi = 0; mi < 4; mi++) {
                ah[mi] = *(const bf16x8*)(AhE + aoff[mi][kh]);
                al[mi] = *(const bf16x8*)(AlE + aoff[mi][kh]);
            }
            #pragma unroll
            for (int ni = 0; ni < 4; ni++) {
                bf16x8 bh = *(const bf16x8*)(BhE + boff[ni][kh]);
                bf16x8 bl = *(const bf16x8*)(BlE + boff[ni][kh]);
                #pragma unroll
                for (int mi = 0; mi < 4; mi++) {
                    acc[mi][ni] = __builtin_amdgcn_mfma_f32_16x16x32_bf16(ah[mi], bh, acc[mi][ni], 0, 0, 0);
                    acc[mi][ni] = __builtin_amdgcn_mfma_f32_16x16x32_bf16(ah[mi], bl, acc[mi][ni], 0, 0, 0);
                    acc[mi][ni] = __builtin_amdgcn_mfma_f32_16x16x32_bf16(al[mi], bh, acc[mi][ni], 0, 0, 0);
                }
            }
        }
    }

    float* Cb = C + (size_t)blockIdx.z * M * N;
    #pragma unroll
    for (int mi = 0; mi < 4; mi++) {
        #pragma unroll
        for (int ni = 0; ni < 4; ni++) {
            int r0 = bm + wm + mi * 16 + q * 4;
            int c0 = bn + wn + ni * 16 + ra;
            Cb[(size_t)(r0 + 0) * N + c0] = acc[mi][ni][0];
            Cb[(size_t)(r0 + 1) * N + c0] = acc[mi][ni][1];
            Cb[(size_t)(r0 + 2) * N + c0] = acc[mi][ni][2];
            Cb[(size_t)(r0 + 3) * N + c0] = acc[mi][ni][3];
        }
    }
}

// ------- fused: sum 8 split-K partials + fp32 out + hi/lo split + norm -------
__global__ __launch_bounds__(256) void k_fuse_xsrc(const float* __restrict__ parts,
                                                   float* __restrict__ xsrc,
                                                   __bf16* __restrict__ xsrc2,
                                                   float* __restrict__ norms) {
    int row = blockIdx.x;
    int c = threadIdx.x * 4;
    size_t off = (size_t)row * DIM + c;
    float4 s = make_float4(0.f, 0.f, 0.f, 0.f);
    #pragma unroll
    for (int z = 0; z < 8; z++) {
        float4 v = *(const float4*)(parts + (size_t)z * (B_ROWS * DIM) + off);
        s.x += v.x; s.y += v.y; s.z += v.z; s.w += v.w;
    }
    *(float4*)(xsrc + off) = s;
    bf16x4 h, l;
    h[0] = split_hi(s.x); l[0] = split_lo(s.x);
    h[1] = split_hi(s.y); l[1] = split_lo(s.y);
    h[2] = split_hi(s.z); l[2] = split_lo(s.z);
    h[3] = split_hi(s.w); l[3] = split_lo(s.w);
    *(bf16x4*)(xsrc2 + (size_t)row * 2048 + c) = h;
    *(bf16x4*)(xsrc2 + (size_t)row * 2048 + 1024 + c) = l;
    float acc = s.x * s.x + s.y * s.y + s.z * s.z + s.w * s.w;
    __shared__ float sm[4];
    float w = wave_sum(acc);
    int lane = threadIdx.x & 63, wid = threadIdx.x >> 6;
    if (lane == 0) sm[wid] = w;
    __syncthreads();
    if (threadIdx.x == 0) norms[row] = sm[0] + sm[1] + sm[2] + sm[3];
}

// ---------------- feature softmax -> split-bf16 w (hi|lo, pitch 16384) --------
__global__ __launch_bounds__(256) void k_softmax_w2(const float* __restrict__ S,
                                                    const float* __restrict__ nx,
                                                    const float* __restrict__ nt,
                                                    __bf16* __restrict__ w2) {
    int row = blockIdx.x;
    const float* sr = S + (size_t)row * NT;
    float nxv = nx[row];
    float vals[NT / 256];
    float lmax = -1e30f;
    #pragma unroll
    for (int u = 0; u < NT / 256; u++) {
        int j = threadIdx.x + u * 256;
        float s = sr[j];
        float sq = nxv + nt[j] - 2.f * s;
        float d = sqrtf(fmaxf(sq, 1e-12f));
        float l = -TEMP * d;
        vals[u] = l;
        lmax = fmaxf(lmax, l);
    }
    __shared__ float sm[4];
    __shared__ float ss[4];
    int lane = threadIdx.x & 63, wid = threadIdx.x >> 6;
    float wm = wave_max(lmax);
    if (lane == 0) sm[wid] = wm;
    __syncthreads();
    float bmax = fmaxf(fmaxf(sm[0], sm[1]), fmaxf(sm[2], sm[3]));
    float lsum = 0.f;
    #pragma unroll
    for (int u = 0; u < NT / 256; u++) {
        float e = __expf(vals[u] - bmax);
        vals[u] = e;
        lsum += e;
    }
    float wsumv = wave_sum(lsum);
    if (lane == 0) ss[wid] = wsumv;
    __syncthreads();
    float bsum = ss[0] + ss[1] + ss[2] + ss[3];
    float inv = 1.0f / bsum;
    __bf16* wr = w2 + (size_t)row * 16384;
    #pragma unroll
    for (int u = 0; u < NT / 256; u++) {
        int j = threadIdx.x + u * 256;
        float w = vals[u] * inv;
        wr[j] = split_hi(w);
        wr[8192 + j] = split_lo(w);
    }
}

// ---------------- classifier head + softmax over 10 classes ----------------
__global__ __launch_bounds__(64) void k_preds(const float* __restrict__ xsrc,
                                              const float* __restrict__ W,
                                              const float* __restrict__ bias,
                                              float* __restrict__ preds) {
    int row = blockIdx.x;
    const float* xr = xsrc + (size_t)row * DIM;
    float acc[NC] = {};
    #pragma unroll
    for (int kk = 0; kk < DIM / 64; kk++) {
        int k = kk * 64 + threadIdx.x;
        float xv = xr[k];
        #pragma unroll
        for (int c = 0; c < NC; c++) acc[c] += xv * W[k * NC + c];
    }
    #pragma unroll
    for (int c = 0; c < NC; c++) acc[c] = wave_sum(acc[c]);
    if (threadIdx.x == 0) {
        float lo[NC];
        float m = -1e30f;
        #pragma unroll
        for (int c = 0; c < NC; c++) {
            lo[c] = acc[c] + bias[c];
            m = fmaxf(m, lo[c]);
        }
        float s = 0.f;
        #pragma unroll
        for (int c = 0; c < NC; c++) {
            lo[c] = __expf(lo[c] - m);
            s += lo[c];
        }
        float inv = 1.0f / s;
        #pragma unroll
        for (int c = 0; c < NC; c++) preds[(size_t)row * NC + c] = lo[c] * inv;
    }
}

// ---------------- M2T[j][c] = sum_k sld[c][k] * shdl[j][k] ----------------
__global__ __launch_bounds__(256) void k_m2t(const float* __restrict__ sld,
                                             const float* __restrict__ shdl,
                                             float* __restrict__ M2T) {
    int idx = blockIdx.x * blockDim.x + threadIdx.x;
    if (idx >= NS * NC) return;
    int j = idx / NC, c = idx % NC;
    float t = 0.f;
    #pragma unroll
    for (int k = 0; k < NC; k++) t += sld[c * NC + k] * shdl[j * NC + k];
    M2T[idx] = t;
}

// ---------------- label transport softmax fused with y = w_lab @ atl ----------
__global__ __launch_bounds__(256) void k_lab_softmax_y(const float* __restrict__ S,
                                                       const float* __restrict__ nx2,
                                                       const float* __restrict__ ns,
                                                       const float* __restrict__ preds,
                                                       const float* __restrict__ M2T,
                                                       const float* __restrict__ atl,
                                                       float* __restrict__ y) {
    int row = blockIdx.x;
    __shared__ float p[NC];
    __shared__ float sm[4];
    __shared__ float ss[4];
    __shared__ float yred[4][NC];
    if (threadIdx.x < NC) p[threadIdx.x] = preds[(size_t)row * NC + threadIdx.x];
    __syncthreads();
    float pr[NC];
    #pragma unroll
    for (int c = 0; c < NC; c++) pr[c] = p[c];
    const float* sr = S + (size_t)row * NS;
    float nxv = nx2[row];
    float vals[NS / 256];
    float lmax = -1e30f;
    #pragma unroll
    for (int u = 0; u < NS / 256; u++) {
        int j = threadIdx.x + u * 256;
        float s = sr[j];
        float sq = nxv + ns[j] - 2.f * s;
        float d = sqrtf(fmaxf(sq, 1e-12f));
        float lab = 0.f;
        #pragma unroll
        for (int c = 0; c < NC; c++) lab += pr[c] * M2T[(size_t)j * NC + c];
        float l = -TEMP * (d + lab);   // ETA = 1
        vals[u] = l;
        lmax = fmaxf(lmax, l);
    }
    int lane = threadIdx.x & 63, wid = threadIdx.x >> 6;
    float wm = wave_max(lmax);
    if (lane == 0) sm[wid] = wm;
    __syncthreads();
    float bmax = fmaxf(fmaxf(sm[0], sm[1]), fmaxf(sm[2], sm[3]));
    float lsum = 0.f;
    #pragma unroll
    for (int u = 0; u < NS / 256; u++) {
        float e = __expf(vals[u] - bmax);
        vals[u] = e;
        lsum += e;
    }
    float wsv = wave_sum(lsum);
    if (lane == 0) ss[wid] = wsv;
    __syncthreads();
    float bsum = ss[0] + ss[1] + ss[2] + ss[3];
    float inv = 1.0f / bsum;
    float yacc[NC] = {};
    #pragma unroll
    for (int u = 0; u < NS / 256; u++) {
        int j = threadIdx.x + u * 256;
        float w = vals[u] * inv;
        #pragma unroll
        for (int c = 0; c < NC; c++) yacc[c] += w * atl[(size_t)j * NC + c];
    }
    #pragma unroll
    for (int c = 0; c < NC; c++) yacc[c] = wave_sum(yacc[c]);
    if (lane == 0) {
        #pragma unroll
        for (int c = 0; c < NC; c++) yred[wid][c] = yacc[c];
    }
    __syncthreads();
    if (threadIdx.x < NC) {
        int c = threadIdx.x;
        y[(size_t)row * NC + c] = yred[0][c] + yred[1][c] + yred[2][c] + yred[3][c];
    }
}

extern "C" void kernel_launch(void* const* d_in, const int* in_sizes, int n_in,
                              void* d_out, int out_size, void* d_ws, size_t ws_size,
                              hipStream_t stream) {
    const float* x    = (const float*)d_in[0];   // [1024, 32, 32]
    const float* tf   = (const float*)d_in[1];   // [8192, 1024]
    const float* asf  = (const float*)d_in[2];   // [8192, 1024]
    const float* sf   = (const float*)d_in[3];   // [8192, 1024]
    const float* shdl = (const float*)d_in[4];   // [8192, 10]
    const float* atl  = (const float*)d_in[5];   // [8192, 10]
    const float* sld  = (const float*)d_in[6];   // [10, 10]
    const float* W    = (const float*)d_in[7];   // [1024, 10]
    const float* bias = (const float*)d_in[8];   // [10]
    float* y = (float*)d_out;                    // [1024, 10]

    char* wsb = (char*)d_ws;
    float*  S     = (float*)(wsb);                          // 32 MiB; aliased by asfT2
    __bf16* asfT2 = (__bf16*)S;                             // [1024][16384]
    float*  BIG1  = (float*)(wsb + (32u << 20));            // 32 MiB: tf2 -> parts -> sf2
    __bf16* tf2   = (__bf16*)BIG1;
    float*  parts = BIG1;                                   // 8 x 4 MiB split-K partials
    __bf16* sf2   = (__bf16*)BIG1;
    __bf16* w2    = (__bf16*)(wsb + (64u << 20));           // 32 MiB
    __bf16* x2    = (__bf16*)(wsb + (96u << 20));           // 4 MiB
    __bf16* xsrc2 = (__bf16*)(wsb + (100u << 20));          // 4 MiB
    float*  xsrc  = (float*)(wsb + (104u << 20));           // 4 MiB
    float*  nt_   = (float*)(wsb + (108u << 20));
    float*  ns_   = nt_ + NT;
    float*  nx_   = ns_ + NS;
    float*  nx2_  = nx_ + B_ROWS;
    float*  preds = nx2_ + B_ROWS;
    float*  M2T   = preds + B_ROWS * NC;

    // fused conversions + norms; label-cost matrix
    k_conv_norm<<<B_ROWS, 256, 0, stream>>>(x, x2, nx_);
    k_conv_norm<<<NT, 256, 0, stream>>>(tf, tf2, nt_);
    k_m2t<<<(NS * NC + 255) / 256, 256, 0, stream>>>(sld, shdl, M2T);

    // G1: S = x @ tf^T   (M=1024, N=8192, K=1024)
    {
        dim3 g(NT / 128, B_ROWS / 128, 1);
        k_gemm3<<<g, 256, 0, stream>>>(x2, tf2, S, B_ROWS, NT, DIM, DIM);
    }
    // w_feat softmax -> split-bf16 w2
    k_softmax_w2<<<B_ROWS, 256, 0, stream>>>(S, nx_, nt_, w2);
    // asf transpose+split into S region (S dead)
    {
        dim3 g(NT / 64, DIM / 64);
        k_conv2t<<<g, 256, 0, stream>>>(asf, asfT2);
    }
    // G2: parts[z] = w2 @ asfT2^T  (M=1024, N=1024, K=8192, split-K x8)
    {
        dim3 g(DIM / 128, B_ROWS / 128, 8);
        k_gemm3<<<g, 256, 0, stream>>>(w2, asfT2, parts, B_ROWS, DIM, NT, NT / 8);
    }
    // fused: reduce8 + xsrc fp32 + hi/lo split + norm
    k_fuse_xsrc<<<B_ROWS, 256, 0, stream>>>(parts, xsrc, xsrc2, nx2_);
    k_preds<<<B_ROWS, 64, 0, stream>>>(xsrc, W, bias, preds);
    // sf conversion + norm (parts dead)
    k_conv_norm<<<NS, 256, 0, stream>>>(sf, sf2, ns_);

    // G3: S = xsrc @ sf^T  (M=1024, N=8192, K=1024)
    {
        dim3 g(NS / 128, B_ROWS / 128, 1);
        k_gemm3<<<g, 256, 0, stream>>>(xsrc2, sf2, S, B_ROWS, NS, DIM, DIM);
    }
    // label softmax + y
    k_lab_softmax_y<<<B_ROWS, 256, 0, stream>>>(S, nx2_, ns_, preds, M2T, atl, y);
}

// Round 5
// 379.751 us; speedup vs baseline: 3.1001x; 1.0010x over previous
//
#include <hip/hip_runtime.h>
#include <hip/hip_bf16.h>
#include <math.h>

#define B_ROWS 1024
#define NT 8192
#define NS 8192
#define DIM 1024
#define NC 10
#define TEMP 100.0f

typedef __bf16 bf16x8 __attribute__((ext_vector_type(8)));
typedef __bf16 bf16x4 __attribute__((ext_vector_type(4)));
typedef float f32x4 __attribute__((ext_vector_type(4)));

#define GLOAD_LDS(g, l) \
    __builtin_amdgcn_global_load_lds((__attribute__((address_space(1))) void*)(g), \
                                     (__attribute__((address_space(3))) void*)(l), 16, 0, 0)

__device__ inline __bf16 split_hi(float v) { return (__bf16)v; }
__device__ inline __bf16 split_lo(float v) {
    __bf16 h = (__bf16)v;
    return (__bf16)(v - (float)h);
}

// ---------------- reduction helpers ----------------
__device__ inline float wave_max(float v) {
    #pragma unroll
    for (int off = 32; off > 0; off >>= 1)
        v = fmaxf(v, __shfl_down(v, off, 64));
    return v;
}
__device__ inline float wave_sum(float v) {
    #pragma unroll
    for (int off = 32; off > 0; off >>= 1)
        v += __shfl_down(v, off, 64);
    return v;
}

// ---------------- fused fp32->bf16 hi/lo split + row norm (rows of 1024) -----
__global__ __launch_bounds__(256) void k_conv_norm(const float* __restrict__ X,
                                                   __bf16* __restrict__ X2,
                                                   float* __restrict__ norms) {
    int row = blockIdx.x;
    int c = threadIdx.x * 4;
    float4 v = *(const float4*)(X + (size_t)row * DIM + c);
    bf16x4 h, l;
    h[0] = split_hi(v.x); l[0] = split_lo(v.x);
    h[1] = split_hi(v.y); l[1] = split_lo(v.y);
    h[2] = split_hi(v.z); l[2] = split_lo(v.z);
    h[3] = split_hi(v.w); l[3] = split_lo(v.w);
    *(bf16x4*)(X2 + (size_t)row * 2048 + c) = h;
    *(bf16x4*)(X2 + (size_t)row * 2048 + 1024 + c) = l;
    float acc = v.x * v.x + v.y * v.y + v.z * v.z + v.w * v.w;
    __shared__ float s[4];
    float w = wave_sum(acc);
    int lane = threadIdx.x & 63, wid = threadIdx.x >> 6;
    if (lane == 0) s[wid] = w;
    __syncthreads();
    if (threadIdx.x == 0) norms[row] = s[0] + s[1] + s[2] + s[3];
}

// ---------------- asf [8192][1024] -> transposed hi/lo split [1024][2*8192] ----
__global__ __launch_bounds__(256) void k_conv2t(const float* __restrict__ X,
                                                __bf16* __restrict__ XT2) {
    __shared__ float t[64][65];
    int k0 = blockIdx.x * 64;  // source row block (k dim, 8192)
    int n0 = blockIdx.y * 64;  // source col block (n dim, 1024)
    int tid = threadIdx.x;
    int tr = tid >> 4;          // 0..15
    int tc = (tid & 15) * 4;    // 0..60
    #pragma unroll
    for (int i = 0; i < 4; i++) {
        int r = tr + i * 16;
        float4 v = *(const float4*)(X + (size_t)(k0 + r) * 1024 + n0 + tc);
        t[r][tc] = v.x; t[r][tc + 1] = v.y; t[r][tc + 2] = v.z; t[r][tc + 3] = v.w;
    }
    __syncthreads();
    #pragma unroll
    for (int i = 0; i < 4; i++) {
        int n = tr + i * 16;   // output row (n), local
        bf16x4 h, l;
        #pragma unroll
        for (int e = 0; e < 4; e++) {
            float v = t[tc + e][n];
            h[e] = split_hi(v);
            l[e] = split_lo(v);
        }
        size_t base = (size_t)(n0 + n) * 16384 + k0 + tc;
        *(bf16x4*)(XT2 + base) = h;
        *(bf16x4*)(XT2 + base + 8192) = l;
    }
}

// ---------------- 3-term split-bf16 MFMA GEMM: C = A*B^T ----------------
// MODE 0: plain fp32 C write (+ blockIdx.z * M*N partials)
// MODE 1: write logits  -TEMP*sqrt(rowN+colN-2*dot)
// MODE 2: write logits  -TEMP*(sqrt(rowN+colN-2*dot) + preds.M2T)
// 128x128 tile, BK=64; LDS row = 128B bank period; chunk XOR (row&7) conflict-free
template <int MODE>
__global__ __launch_bounds__(256) void k_gemm3(const __bf16* __restrict__ A2,
                                               const __bf16* __restrict__ B2,
                                               float* __restrict__ C,
                                               int M, int N, int K, int ksplit,
                                               const float* __restrict__ rowN,
                                               const float* __restrict__ colN,
                                               const float* __restrict__ predsG,
                                               const float* __restrict__ m2tG) {
    __shared__ unsigned short AhS[8192], AlS[8192], BhS[8192], BlS[8192]; // 128x64 each
    __shared__ float extraL[MODE == 2 ? 2816 : (MODE == 1 ? 256 : 1)];
    float* rnL = (MODE == 2) ? extraL + 2560 : extraL;       // [128]
    float* cnL = rnL + (MODE >= 1 ? 128 : 0);                // [128]
    float* predsL = extraL;                                  // [128*10] (MODE 2)
    float* m2tL = extraL + 1280;                             // [128*10] (MODE 2)

    int tid = threadIdx.x;
    int wid = tid >> 6, lane = tid & 63;
    int wm = (wid >> 1) * 64, wn = (wid & 1) * 64;
    int bm = blockIdx.y * 128, bn = blockIdx.x * 128;
    size_t K2 = 2 * (size_t)K;
    int k_begin = blockIdx.z * ksplit;
    int nsteps = ksplit >> 6;

    if (MODE >= 1) {
        if (tid < 128) rnL[tid] = rowN[bm + tid];
        else cnL[tid - 128] = colN[bn + tid - 128];
        if (MODE == 2) {
            for (int i = tid; i < 1280; i += 256) {
                int r = i / 10, c = i - r * 10;
                predsL[i] = predsG[(size_t)(bm + r) * NC + c];
                m2tL[i] = m2tG[(size_t)(bn + r) * NC + c];
            }
        }
    }

    f32x4 acc[4][4];
    #pragma unroll
    for (int i = 0; i < 4; i++)
        #pragma unroll
        for (int j = 0; j < 4; j++) acc[i][j] = (f32x4){0.f, 0.f, 0.f, 0.f};

    // staging: wave wid covers rows [wid*32, wid*32+32), 4 glds passes of 8 rows
    int r_in = lane >> 3;                    // 0..7 row within 8-row pass
    int cgo = ((lane & 7) ^ r_in) * 8;       // swizzled chunk (element offset)
    const __bf16* gA = A2 + (size_t)(bm + wid * 32 + r_in) * K2 + k_begin + cgo;
    const __bf16* gB = B2 + (size_t)(bn + wid * 32 + r_in) * K2 + k_begin + cgo;
    char* AhB = (char*)AhS; char* AlB = (char*)AlS;
    char* BhB = (char*)BhS; char* BlB = (char*)BlS;
    int lbw = wid * 4096;
    size_t row8 = 8 * K2;

    // fragment read offsets (elements), swizzle-compensated
    int ra = lane & 15, q = lane >> 4;
    int aoff[4][2], boff[4][2];
    #pragma unroll
    for (int i = 0; i < 4; i++) {
        #pragma unroll
        for (int kh = 0; kh < 2; kh++) {
            int chunk = ((kh << 2) | q) ^ (ra & 7);
            aoff[i][kh] = (wm + i * 16 + ra) * 64 + chunk * 8;
            boff[i][kh] = (wn + i * 16 + ra) * 64 + chunk * 8;
        }
    }
    const __bf16* AhE = (const __bf16*)AhS;
    const __bf16* AlE = (const __bf16*)AlS;
    const __bf16* BhE = (const __bf16*)BhS;
    const __bf16* BlE = (const __bf16*)BlS;

    for (int ks = 0; ks < nsteps; ks++) {
        __syncthreads();
        #pragma unroll
        for (int p = 0; p < 4; p++) {
            size_t go = p * row8;
            int lo = lbw + p * 1024;
            GLOAD_LDS(gA + go, AhB + lo);
            GLOAD_LDS(gA + go + K, AlB + lo);
            GLOAD_LDS(gB + go, BhB + lo);
            GLOAD_LDS(gB + go + K, BlB + lo);
        }
        gA += 64; gB += 64;
        __syncthreads();

        #pragma unroll
        for (int kh = 0; kh < 2; kh++) {
            bf16x8 ah[4], al[4];
            #pragma unroll
            for (int mi = 0; mi < 4; mi++) {
                ah[mi] = *(const bf16x8*)(AhE + aoff[mi][kh]);
                al[mi] = *(const bf16x8*)(AlE + aoff[mi][kh]);
            }
            #pragma unroll
            for (int ni = 0; ni < 4; ni++) {
                bf16x8 bh = *(const bf16x8*)(BhE + boff[ni][kh]);
                bf16x8 bl = *(const bf16x8*)(BlE + boff[ni][kh]);
                #pragma unroll
                for (int mi = 0; mi < 4; mi++) {
                    acc[mi][ni] = __builtin_amdgcn_mfma_f32_16x16x32_bf16(ah[mi], bh, acc[mi][ni], 0, 0, 0);
                    acc[mi][ni] = __builtin_amdgcn_mfma_f32_16x16x32_bf16(ah[mi], bl, acc[mi][ni], 0, 0, 0);
                    acc[mi][ni] = __builtin_amdgcn_mfma_f32_16x16x32_bf16(al[mi], bh, acc[mi][ni], 0, 0, 0);
                }
            }
        }
    }

    if (MODE == 0) {
        float* Cb = C + (size_t)blockIdx.z * M * N;
        #pragma unroll
        for (int mi = 0; mi < 4; mi++) {
            #pragma unroll
            for (int ni = 0; ni < 4; ni++) {
                int r0 = bm + wm + mi * 16 + q * 4;
                int c0 = bn + wn + ni * 16 + ra;
                Cb[(size_t)(r0 + 0) * N + c0] = acc[mi][ni][0];
                Cb[(size_t)(r0 + 1) * N + c0] = acc[mi][ni][1];
                Cb[(size_t)(r0 + 2) * N + c0] = acc[mi][ni][2];
                Cb[(size_t)(r0 + 3) * N + c0] = acc[mi][ni][3];
            }
        }
    } else {
        float m2tv[4][NC];
        if (MODE == 2) {
            #pragma unroll
            for (int ni = 0; ni < 4; ni++) {
                int cl = wn + ni * 16 + ra;
                #pragma unroll
                for (int c = 0; c < NC; c++) m2tv[ni][c] = m2tL[cl * NC + c];
            }
        }
        #pragma unroll
        for (int mi = 0; mi < 4; mi++) {
            float pv[4][NC];
            if (MODE == 2) {
                #pragma unroll
                for (int i = 0; i < 4; i++) {
                    int rl = wm + mi * 16 + q * 4 + i;
                    #pragma unroll
                    for (int c = 0; c < NC; c++) pv[i][c] = predsL[rl * NC + c];
                }
            }
            #pragma unroll
            for (int ni = 0; ni < 4; ni++) {
                int cl = wn + ni * 16 + ra;
                float cn = cnL[cl];
                #pragma unroll
                for (int i = 0; i < 4; i++) {
                    int rl = wm + mi * 16 + q * 4 + i;
                    float sq = rnL[rl] + cn - 2.f * acc[mi][ni][i];
                    float d = sqrtf(fmaxf(sq, 1e-12f));
                    if (MODE == 2) {
                        float lab = 0.f;
                        #pragma unroll
                        for (int c = 0; c < NC; c++) lab += pv[i][c] * m2tv[ni][c];
                        d += lab;
                    }
                    C[(size_t)(bm + rl) * N + bn + cl] = -TEMP * d;
                }
            }
        }
    }
}

// ------- fused: sum 8 split-K partials + fp32 out + hi/lo split + norm -------
__global__ __launch_bounds__(256) void k_fuse_xsrc(const float* __restrict__ parts,
                                                   float* __restrict__ xsrc,
                                                   __bf16* __restrict__ xsrc2,
                                                   float* __restrict__ norms) {
    int row = blockIdx.x;
    int c = threadIdx.x * 4;
    size_t off = (size_t)row * DIM + c;
    float4 s = make_float4(0.f, 0.f, 0.f, 0.f);
    #pragma unroll
    for (int z = 0; z < 8; z++) {
        float4 v = *(const float4*)(parts + (size_t)z * (B_ROWS * DIM) + off);
        s.x += v.x; s.y += v.y; s.z += v.z; s.w += v.w;
    }
    *(float4*)(xsrc + off) = s;
    bf16x4 h, l;
    h[0] = split_hi(s.x); l[0] = split_lo(s.x);
    h[1] = split_hi(s.y); l[1] = split_lo(s.y);
    h[2] = split_hi(s.z); l[2] = split_lo(s.z);
    h[3] = split_hi(s.w); l[3] = split_lo(s.w);
    *(bf16x4*)(xsrc2 + (size_t)row * 2048 + c) = h;
    *(bf16x4*)(xsrc2 + (size_t)row * 2048 + 1024 + c) = l;
    float acc = s.x * s.x + s.y * s.y + s.z * s.z + s.w * s.w;
    __shared__ float sm[4];
    float w = wave_sum(acc);
    int lane = threadIdx.x & 63, wid = threadIdx.x >> 6;
    if (lane == 0) sm[wid] = w;
    __syncthreads();
    if (threadIdx.x == 0) norms[row] = sm[0] + sm[1] + sm[2] + sm[3];
}

// ---------------- feature softmax (input = logits) -> split-bf16 w ------------
__global__ __launch_bounds__(256) void k_softmax_w2(const float* __restrict__ S,
                                                    __bf16* __restrict__ w2) {
    int row = blockIdx.x;
    const float* sr = S + (size_t)row * NT;
    float vals[NT / 256];
    float lmax = -1e30f;
    #pragma unroll
    for (int u = 0; u < NT / 256; u++) {
        int j = threadIdx.x + u * 256;
        float l = sr[j];
        vals[u] = l;
        lmax = fmaxf(lmax, l);
    }
    __shared__ float sm[4];
    __shared__ float ss[4];
    int lane = threadIdx.x & 63, wid = threadIdx.x >> 6;
    float wm = wave_max(lmax);
    if (lane == 0) sm[wid] = wm;
    __syncthreads();
    float bmax = fmaxf(fmaxf(sm[0], sm[1]), fmaxf(sm[2], sm[3]));
    float lsum = 0.f;
    #pragma unroll
    for (int u = 0; u < NT / 256; u++) {
        float e = __expf(vals[u] - bmax);
        vals[u] = e;
        lsum += e;
    }
    float wsumv = wave_sum(lsum);
    if (lane == 0) ss[wid] = wsumv;
    __syncthreads();
    float bsum = ss[0] + ss[1] + ss[2] + ss[3];
    float inv = 1.0f / bsum;
    __bf16* wr = w2 + (size_t)row * 16384;
    #pragma unroll
    for (int u = 0; u < NT / 256; u++) {
        int j = threadIdx.x + u * 256;
        float w = vals[u] * inv;
        wr[j] = split_hi(w);
        wr[8192 + j] = split_lo(w);
    }
}

// ---------------- classifier head + softmax over 10 classes ----------------
__global__ __launch_bounds__(64) void k_preds(const float* __restrict__ xsrc,
                                              const float* __restrict__ W,
                                              const float* __restrict__ bias,
                                              float* __restrict__ preds) {
    int row = blockIdx.x;
    const float* xr = xsrc + (size_t)row * DIM;
    float acc[NC] = {};
    #pragma unroll
    for (int kk = 0; kk < DIM / 64; kk++) {
        int k = kk * 64 + threadIdx.x;
        float xv = xr[k];
        #pragma unroll
        for (int c = 0; c < NC; c++) acc[c] += xv * W[k * NC + c];
    }
    #pragma unroll
    for (int c = 0; c < NC; c++) acc[c] = wave_sum(acc[c]);
    if (threadIdx.x == 0) {
        float lo[NC];
        float m = -1e30f;
        #pragma unroll
        for (int c = 0; c < NC; c++) {
            lo[c] = acc[c] + bias[c];
            m = fmaxf(m, lo[c]);
        }
        float s = 0.f;
        #pragma unroll
        for (int c = 0; c < NC; c++) {
            lo[c] = __expf(lo[c] - m);
            s += lo[c];
        }
        float inv = 1.0f / s;
        #pragma unroll
        for (int c = 0; c < NC; c++) preds[(size_t)row * NC + c] = lo[c] * inv;
    }
}

// ---------------- M2T[j][c] = sum_k sld[c][k] * shdl[j][k] ----------------
__global__ __launch_bounds__(256) void k_m2t(const float* __restrict__ sld,
                                             const float* __restrict__ shdl,
                                             float* __restrict__ M2T) {
    int idx = blockIdx.x * blockDim.x + threadIdx.x;
    if (idx >= NS * NC) return;
    int j = idx / NC, c = idx % NC;
    float t = 0.f;
    #pragma unroll
    for (int k = 0; k < NC; k++) t += sld[c * NC + k] * shdl[j * NC + k];
    M2T[idx] = t;
}

// ---------------- atl [8192][10] -> atlt [10][8192] ----------------
__global__ __launch_bounds__(256) void k_t_atl(const float* __restrict__ atl,
                                               float* __restrict__ atlt) {
    int j = blockIdx.x * 256 + threadIdx.x;
    #pragma unroll
    for (int c = 0; c < NC; c++) atlt[c * NS + j] = atl[(size_t)j * NC + c];
}

// ------- label softmax (input = logits) fused with y = w_lab @ atl ----------
__global__ __launch_bounds__(256) void k_lab_softmax_y(const float* __restrict__ S,
                                                       const float* __restrict__ atlt,
                                                       float* __restrict__ y) {
    int row = blockIdx.x;
    const float* sr = S + (size_t)row * NS;
    float vals[NS / 256];
    float lmax = -1e30f;
    #pragma unroll
    for (int u = 0; u < NS / 256; u++) {
        int j = threadIdx.x + u * 256;
        float l = sr[j];
        vals[u] = l;
        lmax = fmaxf(lmax, l);
    }
    __shared__ float sm[4];
    __shared__ float ss[4];
    __shared__ float yred[4][NC];
    int lane = threadIdx.x & 63, wid = threadIdx.x >> 6;
    float wm = wave_max(lmax);
    if (lane == 0) sm[wid] = wm;
    __syncthreads();
    float bmax = fmaxf(fmaxf(sm[0], sm[1]), fmaxf(sm[2], sm[3]));
    float lsum = 0.f;
    #pragma unroll
    for (int u = 0; u < NS / 256; u++) {
        float e = __expf(vals[u] - bmax);
        vals[u] = e;
        lsum += e;
    }
    float wsv = wave_sum(lsum);
    if (lane == 0) ss[wid] = wsv;
    __syncthreads();
    float bsum = ss[0] + ss[1] + ss[2] + ss[3];
    float inv = 1.0f / bsum;
    float yacc[NC] = {};
    #pragma unroll
    for (int u = 0; u < NS / 256; u++) {
        int j = threadIdx.x + u * 256;
        float w = vals[u] * inv;
        #pragma unroll
        for (int c = 0; c < NC; c++) yacc[c] += w * atlt[c * NS + j];
    }
    #pragma unroll
    for (int c = 0; c < NC; c++) yacc[c] = wave_sum(yacc[c]);
    if (lane == 0) {
        #pragma unroll
        for (int c = 0; c < NC; c++) yred[wid][c] = yacc[c];
    }
    __syncthreads();
    if (threadIdx.x < NC) {
        int c = threadIdx.x;
        y[(size_t)row * NC + c] = yred[0][c] + yred[1][c] + yred[2][c] + yred[3][c];
    }
}

extern "C" void kernel_launch(void* const* d_in, const int* in_sizes, int n_in,
                              void* d_out, int out_size, void* d_ws, size_t ws_size,
                              hipStream_t stream) {
    const float* x    = (const float*)d_in[0];   // [1024, 32, 32]
    const float* tf   = (const float*)d_in[1];   // [8192, 1024]
    const float* asf  = (const float*)d_in[2];   // [8192, 1024]
    const float* sf   = (const float*)d_in[3];   // [8192, 1024]
    const float* shdl = (const float*)d_in[4];   // [8192, 10]
    const float* atl  = (const float*)d_in[5];   // [8192, 10]
    const float* sld  = (const float*)d_in[6];   // [10, 10]
    const float* W    = (const float*)d_in[7];   // [1024, 10]
    const float* bias = (const float*)d_in[8];   // [10]
    float* y = (float*)d_out;                    // [1024, 10]

    char* wsb = (char*)d_ws;
    float*  S     = (float*)(wsb);                          // 32 MiB; aliased by asfT2
    __bf16* asfT2 = (__bf16*)S;                             // [1024][16384]
    float*  BIG1  = (float*)(wsb + (32u << 20));            // 32 MiB: tf2 -> parts -> sf2
    __bf16* tf2   = (__bf16*)BIG1;
    float*  parts = BIG1;                                   // 8 x 4 MiB split-K partials
    __bf16* sf2   = (__bf16*)BIG1;
    __bf16* w2    = (__bf16*)(wsb + (64u << 20));           // 32 MiB
    __bf16* x2    = (__bf16*)(wsb + (96u << 20));           // 4 MiB
    __bf16* xsrc2 = (__bf16*)(wsb + (100u << 20));          // 4 MiB
    float*  xsrc  = (float*)(wsb + (104u << 20));           // 4 MiB
    float*  nt_   = (float*)(wsb + (108u << 20));
    float*  ns_   = nt_ + NT;
    float*  nx_   = ns_ + NS;
    float*  nx2_  = nx_ + B_ROWS;
    float*  preds = nx2_ + B_ROWS;
    float*  M2T   = preds + B_ROWS * NC;
    float*  atlt  = M2T + NS * NC;

    // fused conversions + norms; label matrices
    k_conv_norm<<<B_ROWS, 256, 0, stream>>>(x, x2, nx_);
    k_conv_norm<<<NT, 256, 0, stream>>>(tf, tf2, nt_);
    k_m2t<<<(NS * NC + 255) / 256, 256, 0, stream>>>(sld, shdl, M2T);
    k_t_atl<<<NS / 256, 256, 0, stream>>>(atl, atlt);

    // G1: S = logits(-TEMP*d(x, tf))   (M=1024, N=8192, K=1024)
    {
        dim3 g(NT / 128, B_ROWS / 128, 1);
        k_gemm3<1><<<g, 256, 0, stream>>>(x2, tf2, S, B_ROWS, NT, DIM, DIM,
                                          nx_, nt_, nullptr, nullptr);
    }
    // w_feat softmax -> split-bf16 w2
    k_softmax_w2<<<B_ROWS, 256, 0, stream>>>(S, w2);
    // asf transpose+split into S region (S dead)
    {
        dim3 g(NT / 64, DIM / 64);
        k_conv2t<<<g, 256, 0, stream>>>(asf, asfT2);
    }
    // G2: parts[z] = w2 @ asfT2^T  (M=1024, N=1024, K=8192, split-K x8)
    {
        dim3 g(DIM / 128, B_ROWS / 128, 8);
        k_gemm3<0><<<g, 256, 0, stream>>>(w2, asfT2, parts, B_ROWS, DIM, NT, NT / 8,
                                          nullptr, nullptr, nullptr, nullptr);
    }
    // fused: reduce8 + xsrc fp32 + hi/lo split + norm
    k_fuse_xsrc<<<B_ROWS, 256, 0, stream>>>(parts, xsrc, xsrc2, nx2_);
    k_preds<<<B_ROWS, 64, 0, stream>>>(xsrc, W, bias, preds);
    // sf conversion + norm (parts dead)
    k_conv_norm<<<NS, 256, 0, stream>>>(sf, sf2, ns_);

    // G3: S = logits(-TEMP*(d(xsrc, sf) + preds.M2T))  (M=1024, N=8192, K=1024)
    {
        dim3 g(NS / 128, B_ROWS / 128, 1);
        k_gemm3<2><<<g, 256, 0, stream>>>(xsrc2, sf2, S, B_ROWS, NS, DIM, DIM,
                                          nx2_, ns_, preds, M2T);
    }
    // label softmax + y
    k_lab_softmax_y<<<B_ROWS, 256, 0, stream>>>(S, atlt, y);
}

// Round 6
// 345.535 us; speedup vs baseline: 3.4071x; 1.0990x over previous
//
#include <hip/hip_runtime.h>
#include <hip/hip_bf16.h>
#include <math.h>

#define B_ROWS 1024
#define NT 8192
#define NS 8192
#define DIM 1024
#define NC 10
#define TEMP 100.0f

typedef __bf16 bf16x8 __attribute__((ext_vector_type(8)));
typedef __bf16 bf16x4 __attribute__((ext_vector_type(4)));
typedef float f32x4 __attribute__((ext_vector_type(4)));

#define GLOAD_LDS(g, l) \
    __builtin_amdgcn_global_load_lds((__attribute__((address_space(1))) void*)(g), \
                                     (__attribute__((address_space(3))) void*)(l), 16, 0, 0)

__device__ inline __bf16 split_hi(float v) { return (__bf16)v; }
__device__ inline __bf16 split_lo(float v) {
    __bf16 h = (__bf16)v;
    return (__bf16)(v - (float)h);
}

// ---------------- reduction helpers ----------------
__device__ inline float wave_max(float v) {
    #pragma unroll
    for (int off = 32; off > 0; off >>= 1)
        v = fmaxf(v, __shfl_down(v, off, 64));
    return v;
}
__device__ inline float wave_sum(float v) {
    #pragma unroll
    for (int off = 32; off > 0; off >>= 1)
        v += __shfl_down(v, off, 64);
    return v;
}

// ---------------- fused fp32->bf16 hi/lo split + row norm (rows of 1024) -----
__global__ __launch_bounds__(256) void k_conv_norm(const float* __restrict__ X,
                                                   __bf16* __restrict__ X2,
                                                   float* __restrict__ norms) {
    int row = blockIdx.x;
    int c = threadIdx.x * 4;
    float4 v = *(const float4*)(X + (size_t)row * DIM + c);
    bf16x4 h, l;
    h[0] = split_hi(v.x); l[0] = split_lo(v.x);
    h[1] = split_hi(v.y); l[1] = split_lo(v.y);
    h[2] = split_hi(v.z); l[2] = split_lo(v.z);
    h[3] = split_hi(v.w); l[3] = split_lo(v.w);
    *(bf16x4*)(X2 + (size_t)row * 2048 + c) = h;
    *(bf16x4*)(X2 + (size_t)row * 2048 + 1024 + c) = l;
    float acc = v.x * v.x + v.y * v.y + v.z * v.z + v.w * v.w;
    __shared__ float s[4];
    float w = wave_sum(acc);
    int lane = threadIdx.x & 63, wid = threadIdx.x >> 6;
    if (lane == 0) s[wid] = w;
    __syncthreads();
    if (threadIdx.x == 0) norms[row] = s[0] + s[1] + s[2] + s[3];
}

// ---------------- asf [8192][1024] -> transposed hi/lo split [1024][2*8192] ----
__global__ __launch_bounds__(256) void k_conv2t(const float* __restrict__ X,
                                                __bf16* __restrict__ XT2) {
    __shared__ float t[64][65];
    int k0 = blockIdx.x * 64;  // source row block (k dim, 8192)
    int n0 = blockIdx.y * 64;  // source col block (n dim, 1024)
    int tid = threadIdx.x;
    int tr = tid >> 4;          // 0..15
    int tc = (tid & 15) * 4;    // 0..60
    #pragma unroll
    for (int i = 0; i < 4; i++) {
        int r = tr + i * 16;
        float4 v = *(const float4*)(X + (size_t)(k0 + r) * 1024 + n0 + tc);
        t[r][tc] = v.x; t[r][tc + 1] = v.y; t[r][tc + 2] = v.z; t[r][tc + 3] = v.w;
    }
    __syncthreads();
    #pragma unroll
    for (int i = 0; i < 4; i++) {
        int n = tr + i * 16;   // output row (n), local
        bf16x4 h, l;
        #pragma unroll
        for (int e = 0; e < 4; e++) {
            float v = t[tc + e][n];
            h[e] = split_hi(v);
            l[e] = split_lo(v);
        }
        size_t base = (size_t)(n0 + n) * 16384 + k0 + tc;
        *(bf16x4*)(XT2 + base) = h;
        *(bf16x4*)(XT2 + base + 8192) = l;
    }
}

// ---------------- 3-term split-bf16 MFMA GEMM: C = A*B^T ----------------
// LOGITS=false: plain fp32 C write (+ blockIdx.z * M*N partials)
// LOGITS=true:  write logits  -TEMP*sqrt(rowN+colN-2*dot)
// 128x128 tile, BK=64; LDS row = 128B bank period; chunk XOR (row&7) conflict-free
template <bool LOGITS>
__global__ __launch_bounds__(256) void k_gemm3(const __bf16* __restrict__ A2,
                                               const __bf16* __restrict__ B2,
                                               float* __restrict__ C,
                                               int M, int N, int K, int ksplit,
                                               const float* __restrict__ rowN,
                                               const float* __restrict__ colN) {
    __shared__ unsigned short AhS[8192], AlS[8192], BhS[8192], BlS[8192]; // 128x64 each
    __shared__ float extraL[LOGITS ? 256 : 2];
    float* rnL = extraL;                    // [128]
    float* cnL = extraL + 128;              // [128]

    int tid = threadIdx.x;
    int wid = tid >> 6, lane = tid & 63;
    int wm = (wid >> 1) * 64, wn = (wid & 1) * 64;
    int bm = blockIdx.y * 128, bn = blockIdx.x * 128;
    size_t K2 = 2 * (size_t)K;
    int k_begin = blockIdx.z * ksplit;
    int nsteps = ksplit >> 6;

    if (LOGITS) {
        if (tid < 128) rnL[tid] = rowN[bm + tid];
        else cnL[tid - 128] = colN[bn + tid - 128];
    }

    f32x4 acc[4][4];
    #pragma unroll
    for (int i = 0; i < 4; i++)
        #pragma unroll
        for (int j = 0; j < 4; j++) acc[i][j] = (f32x4){0.f, 0.f, 0.f, 0.f};

    // staging: wave wid covers rows [wid*32, wid*32+32), 4 glds passes of 8 rows
    int r_in = lane >> 3;                    // 0..7 row within 8-row pass
    int cgo = ((lane & 7) ^ r_in) * 8;       // swizzled chunk (element offset)
    const __bf16* gA = A2 + (size_t)(bm + wid * 32 + r_in) * K2 + k_begin + cgo;
    const __bf16* gB = B2 + (size_t)(bn + wid * 32 + r_in) * K2 + k_begin + cgo;
    char* AhB = (char*)AhS; char* AlB = (char*)AlS;
    char* BhB = (char*)BhS; char* BlB = (char*)BlS;
    int lbw = wid * 4096;
    size_t row8 = 8 * K2;

    // fragment read offsets (elements), swizzle-compensated
    int ra = lane & 15, q = lane >> 4;
    int aoff[4][2], boff[4][2];
    #pragma unroll
    for (int i = 0; i < 4; i++) {
        #pragma unroll
        for (int kh = 0; kh < 2; kh++) {
            int chunk = ((kh << 2) | q) ^ (ra & 7);
            aoff[i][kh] = (wm + i * 16 + ra) * 64 + chunk * 8;
            boff[i][kh] = (wn + i * 16 + ra) * 64 + chunk * 8;
        }
    }
    const __bf16* AhE = (const __bf16*)AhS;
    const __bf16* AlE = (const __bf16*)AlS;
    const __bf16* BhE = (const __bf16*)BhS;
    const __bf16* BlE = (const __bf16*)BlS;

    for (int ks = 0; ks < nsteps; ks++) {
        __syncthreads();
        #pragma unroll
        for (int p = 0; p < 4; p++) {
            size_t go = p * row8;
            int lo = lbw + p * 1024;
            GLOAD_LDS(gA + go, AhB + lo);
            GLOAD_LDS(gA + go + K, AlB + lo);
            GLOAD_LDS(gB + go, BhB + lo);
            GLOAD_LDS(gB + go + K, BlB + lo);
        }
        gA += 64; gB += 64;
        __syncthreads();

        #pragma unroll
        for (int kh = 0; kh < 2; kh++) {
            bf16x8 ah[4], al[4];
            #pragma unroll
            for (int mi = 0; mi < 4; mi++) {
                ah[mi] = *(const bf16x8*)(AhE + aoff[mi][kh]);
                al[mi] = *(const bf16x8*)(AlE + aoff[mi][kh]);
            }
            #pragma unroll
            for (int ni = 0; ni < 4; ni++) {
                bf16x8 bh = *(const bf16x8*)(BhE + boff[ni][kh]);
                bf16x8 bl = *(const bf16x8*)(BlE + boff[ni][kh]);
                #pragma unroll
                for (int mi = 0; mi < 4; mi++) {
                    acc[mi][ni] = __builtin_amdgcn_mfma_f32_16x16x32_bf16(ah[mi], bh, acc[mi][ni], 0, 0, 0);
                    acc[mi][ni] = __builtin_amdgcn_mfma_f32_16x16x32_bf16(ah[mi], bl, acc[mi][ni], 0, 0, 0);
                    acc[mi][ni] = __builtin_amdgcn_mfma_f32_16x16x32_bf16(al[mi], bh, acc[mi][ni], 0, 0, 0);
                }
            }
        }
    }

    if (!LOGITS) {
        float* Cb = C + (size_t)blockIdx.z * M * N;
        #pragma unroll
        for (int mi = 0; mi < 4; mi++) {
            #pragma unroll
            for (int ni = 0; ni < 4; ni++) {
                int r0 = bm + wm + mi * 16 + q * 4;
                int c0 = bn + wn + ni * 16 + ra;
                Cb[(size_t)(r0 + 0) * N + c0] = acc[mi][ni][0];
                Cb[(size_t)(r0 + 1) * N + c0] = acc[mi][ni][1];
                Cb[(size_t)(r0 + 2) * N + c0] = acc[mi][ni][2];
                Cb[(size_t)(r0 + 3) * N + c0] = acc[mi][ni][3];
            }
        }
    } else {
        #pragma unroll
        for (int mi = 0; mi < 4; mi++) {
            #pragma unroll
            for (int ni = 0; ni < 4; ni++) {
                int cl = wn + ni * 16 + ra;
                float cn = cnL[cl];
                #pragma unroll
                for (int i = 0; i < 4; i++) {
                    int rl = wm + mi * 16 + q * 4 + i;
                    float sq = rnL[rl] + cn - 2.f * acc[mi][ni][i];
                    float d = sqrtf(fmaxf(sq, 1e-12f));
                    C[(size_t)(bm + rl) * N + bn + cl] = -TEMP * d;
                }
            }
        }
    }
}

// ------- fused: sum 8 split-K partials + fp32 out + hi/lo split + norm -------
__global__ __launch_bounds__(256) void k_fuse_xsrc(const float* __restrict__ parts,
                                                   float* __restrict__ xsrc,
                                                   __bf16* __restrict__ xsrc2,
                                                   float* __restrict__ norms) {
    int row = blockIdx.x;
    int c = threadIdx.x * 4;
    size_t off = (size_t)row * DIM + c;
    float4 s = make_float4(0.f, 0.f, 0.f, 0.f);
    #pragma unroll
    for (int z = 0; z < 8; z++) {
        float4 v = *(const float4*)(parts + (size_t)z * (B_ROWS * DIM) + off);
        s.x += v.x; s.y += v.y; s.z += v.z; s.w += v.w;
    }
    *(float4*)(xsrc + off) = s;
    bf16x4 h, l;
    h[0] = split_hi(s.x); l[0] = split_lo(s.x);
    h[1] = split_hi(s.y); l[1] = split_lo(s.y);
    h[2] = split_hi(s.z); l[2] = split_lo(s.z);
    h[3] = split_hi(s.w); l[3] = split_lo(s.w);
    *(bf16x4*)(xsrc2 + (size_t)row * 2048 + c) = h;
    *(bf16x4*)(xsrc2 + (size_t)row * 2048 + 1024 + c) = l;
    float acc = s.x * s.x + s.y * s.y + s.z * s.z + s.w * s.w;
    __shared__ float sm[4];
    float w = wave_sum(acc);
    int lane = threadIdx.x & 63, wid = threadIdx.x >> 6;
    if (lane == 0) sm[wid] = w;
    __syncthreads();
    if (threadIdx.x == 0) norms[row] = sm[0] + sm[1] + sm[2] + sm[3];
}

// ---------------- feature softmax (input = logits) -> split-bf16 w ------------
__global__ __launch_bounds__(256) void k_softmax_w2(const float* __restrict__ S,
                                                    __bf16* __restrict__ w2) {
    int row = blockIdx.x;
    const float* sr = S + (size_t)row * NT;
    float vals[NT / 256];
    float lmax = -1e30f;
    #pragma unroll
    for (int u = 0; u < NT / 256; u++) {
        int j = threadIdx.x + u * 256;
        float l = sr[j];
        vals[u] = l;
        lmax = fmaxf(lmax, l);
    }
    __shared__ float sm[4];
    __shared__ float ss[4];
    int lane = threadIdx.x & 63, wid = threadIdx.x >> 6;
    float wm = wave_max(lmax);
    if (lane == 0) sm[wid] = wm;
    __syncthreads();
    float bmax = fmaxf(fmaxf(sm[0], sm[1]), fmaxf(sm[2], sm[3]));
    float lsum = 0.f;
    #pragma unroll
    for (int u = 0; u < NT / 256; u++) {
        float e = __expf(vals[u] - bmax);
        vals[u] = e;
        lsum += e;
    }
    float wsumv = wave_sum(lsum);
    if (lane == 0) ss[wid] = wsumv;
    __syncthreads();
    float bsum = ss[0] + ss[1] + ss[2] + ss[3];
    float inv = 1.0f / bsum;
    __bf16* wr = w2 + (size_t)row * 16384;
    #pragma unroll
    for (int u = 0; u < NT / 256; u++) {
        int j = threadIdx.x + u * 256;
        float w = vals[u] * inv;
        wr[j] = split_hi(w);
        wr[8192 + j] = split_lo(w);
    }
}

// ---------------- classifier head + softmax over 10 classes ----------------
__global__ __launch_bounds__(64) void k_preds(const float* __restrict__ xsrc,
                                              const float* __restrict__ W,
                                              const float* __restrict__ bias,
                                              float* __restrict__ preds) {
    int row = blockIdx.x;
    const float* xr = xsrc + (size_t)row * DIM;
    float acc[NC] = {};
    #pragma unroll
    for (int kk = 0; kk < DIM / 64; kk++) {
        int k = kk * 64 + threadIdx.x;
        float xv = xr[k];
        #pragma unroll
        for (int c = 0; c < NC; c++) acc[c] += xv * W[k * NC + c];
    }
    #pragma unroll
    for (int c = 0; c < NC; c++) acc[c] = wave_sum(acc[c]);
    if (threadIdx.x == 0) {
        float lo[NC];
        float m = -1e30f;
        #pragma unroll
        for (int c = 0; c < NC; c++) {
            lo[c] = acc[c] + bias[c];
            m = fmaxf(m, lo[c]);
        }
        float s = 0.f;
        #pragma unroll
        for (int c = 0; c < NC; c++) {
            lo[c] = __expf(lo[c] - m);
            s += lo[c];
        }
        float inv = 1.0f / s;
        #pragma unroll
        for (int c = 0; c < NC; c++) preds[(size_t)row * NC + c] = lo[c] * inv;
    }
}

// ------- prep: M2Tt[c][j] = sum_k sld[c][k]*shdl[j][k];  atlt[c][j] = atl[j][c]
__global__ __launch_bounds__(256) void k_prep_labels(const float* __restrict__ sld,
                                                     const float* __restrict__ shdl,
                                                     const float* __restrict__ atl,
                                                     float* __restrict__ M2Tt,
                                                     float* __restrict__ atlt) {
    __shared__ float sldL[NC * NC];
    if (threadIdx.x < NC * NC) sldL[threadIdx.x] = sld[threadIdx.x];
    __syncthreads();
    int j = blockIdx.x * 256 + threadIdx.x;
    float sh[NC], at[NC];
    #pragma unroll
    for (int k = 0; k < NC; k++) sh[k] = shdl[(size_t)j * NC + k];
    #pragma unroll
    for (int c = 0; c < NC; c++) at[c] = atl[(size_t)j * NC + c];
    #pragma unroll
    for (int c = 0; c < NC; c++) {
        float t = 0.f;
        #pragma unroll
        for (int k = 0; k < NC; k++) t += sldL[c * NC + k] * sh[k];
        M2Tt[c * NS + j] = t;
        atlt[c * NS + j] = at[c];
    }
}

// ------- label softmax + y, 2 rows per block ---------------------------------
// logits = S[row][j] - TEMP * sum_c preds[row][c]*M2Tt[c][j]
__global__ __launch_bounds__(256) void k_lab_softmax_y(const float* __restrict__ S,
                                                       const float* __restrict__ predsG,
                                                       const float* __restrict__ M2Tt,
                                                       const float* __restrict__ atlt,
                                                       float* __restrict__ y) {
    int r0 = blockIdx.x * 2, r1 = r0 + 1;
    float pr0[NC], pr1[NC];
    #pragma unroll
    for (int c = 0; c < NC; c++) {
        pr0[c] = predsG[(size_t)r0 * NC + c];
        pr1[c] = predsG[(size_t)r1 * NC + c];
    }
    const float* s0 = S + (size_t)r0 * NS;
    const float* s1 = S + (size_t)r1 * NS;
    float v0[NS / 256], v1[NS / 256];
    float m0 = -1e30f, m1 = -1e30f;
    #pragma unroll
    for (int u = 0; u < NS / 256; u++) {
        int j = threadIdx.x + u * 256;
        float lab0 = 0.f, lab1 = 0.f;
        #pragma unroll
        for (int c = 0; c < NC; c++) {
            float mv = M2Tt[c * NS + j];
            lab0 += pr0[c] * mv;
            lab1 += pr1[c] * mv;
        }
        float l0 = s0[j] - TEMP * lab0;
        float l1 = s1[j] - TEMP * lab1;
        v0[u] = l0; v1[u] = l1;
        m0 = fmaxf(m0, l0); m1 = fmaxf(m1, l1);
    }
    __shared__ float sm[2][4];
    __shared__ float ss[2][4];
    __shared__ float yred[4][2][NC];
    int lane = threadIdx.x & 63, wid = threadIdx.x >> 6;
    float wm0 = wave_max(m0), wm1 = wave_max(m1);
    if (lane == 0) { sm[0][wid] = wm0; sm[1][wid] = wm1; }
    __syncthreads();
    float bm0 = fmaxf(fmaxf(sm[0][0], sm[0][1]), fmaxf(sm[0][2], sm[0][3]));
    float bm1 = fmaxf(fmaxf(sm[1][0], sm[1][1]), fmaxf(sm[1][2], sm[1][3]));
    float ls0 = 0.f, ls1 = 0.f;
    #pragma unroll
    for (int u = 0; u < NS / 256; u++) {
        float e0 = __expf(v0[u] - bm0);
        float e1 = __expf(v1[u] - bm1);
        v0[u] = e0; v1[u] = e1;
        ls0 += e0; ls1 += e1;
    }
    float ws0 = wave_sum(ls0), ws1 = wave_sum(ls1);
    if (lane == 0) { ss[0][wid] = ws0; ss[1][wid] = ws1; }
    __syncthreads();
    float inv0 = 1.0f / (ss[0][0] + ss[0][1] + ss[0][2] + ss[0][3]);
    float inv1 = 1.0f / (ss[1][0] + ss[1][1] + ss[1][2] + ss[1][3]);
    float y0[NC] = {}, y1[NC] = {};
    #pragma unroll
    for (int u = 0; u < NS / 256; u++) {
        int j = threadIdx.x + u * 256;
        float w0 = v0[u] * inv0;
        float w1 = v1[u] * inv1;
        #pragma unroll
        for (int c = 0; c < NC; c++) {
            float av = atlt[c * NS + j];
            y0[c] += w0 * av;
            y1[c] += w1 * av;
        }
    }
    #pragma unroll
    for (int c = 0; c < NC; c++) { y0[c] = wave_sum(y0[c]); y1[c] = wave_sum(y1[c]); }
    if (lane == 0) {
        #pragma unroll
        for (int c = 0; c < NC; c++) { yred[wid][0][c] = y0[c]; yred[wid][1][c] = y1[c]; }
    }
    __syncthreads();
    if (threadIdx.x < 2 * NC) {
        int r = threadIdx.x / NC, c = threadIdx.x - r * NC;
        y[(size_t)(r0 + r) * NC + c] = yred[0][r][c] + yred[1][r][c] + yred[2][r][c] + yred[3][r][c];
    }
}

extern "C" void kernel_launch(void* const* d_in, const int* in_sizes, int n_in,
                              void* d_out, int out_size, void* d_ws, size_t ws_size,
                              hipStream_t stream) {
    const float* x    = (const float*)d_in[0];   // [1024, 32, 32]
    const float* tf   = (const float*)d_in[1];   // [8192, 1024]
    const float* asf  = (const float*)d_in[2];   // [8192, 1024]
    const float* sf   = (const float*)d_in[3];   // [8192, 1024]
    const float* shdl = (const float*)d_in[4];   // [8192, 10]
    const float* atl  = (const float*)d_in[5];   // [8192, 10]
    const float* sld  = (const float*)d_in[6];   // [10, 10]
    const float* W    = (const float*)d_in[7];   // [1024, 10]
    const float* bias = (const float*)d_in[8];   // [10]
    float* y = (float*)d_out;                    // [1024, 10]

    char* wsb = (char*)d_ws;
    float*  S     = (float*)(wsb);                          // 32 MiB; aliased by asfT2
    __bf16* asfT2 = (__bf16*)S;                             // [1024][16384]
    float*  BIG1  = (float*)(wsb + (32u << 20));            // 32 MiB: tf2 -> parts -> sf2
    __bf16* tf2   = (__bf16*)BIG1;
    float*  parts = BIG1;                                   // 8 x 4 MiB split-K partials
    __bf16* sf2   = (__bf16*)BIG1;
    __bf16* w2    = (__bf16*)(wsb + (64u << 20));           // 32 MiB
    __bf16* x2    = (__bf16*)(wsb + (96u << 20));           // 4 MiB
    __bf16* xsrc2 = (__bf16*)(wsb + (100u << 20));          // 4 MiB
    float*  xsrc  = (float*)(wsb + (104u << 20));           // 4 MiB
    float*  nt_   = (float*)(wsb + (108u << 20));
    float*  ns_   = nt_ + NT;
    float*  nx_   = ns_ + NS;
    float*  nx2_  = nx_ + B_ROWS;
    float*  preds = nx2_ + B_ROWS;
    float*  M2Tt  = preds + B_ROWS * NC;                    // [10][8192]
    float*  atlt  = M2Tt + NS * NC;                         // [10][8192]

    // fused conversions + norms; label matrices (transposed)
    k_conv_norm<<<B_ROWS, 256, 0, stream>>>(x, x2, nx_);
    k_conv_norm<<<NT, 256, 0, stream>>>(tf, tf2, nt_);
    k_prep_labels<<<NS / 256, 256, 0, stream>>>(sld, shdl, atl, M2Tt, atlt);

    // G1: S = logits(-TEMP*d(x, tf))   (M=1024, N=8192, K=1024)
    {
        dim3 g(NT / 128, B_ROWS / 128, 1);
        k_gemm3<true><<<g, 256, 0, stream>>>(x2, tf2, S, B_ROWS, NT, DIM, DIM,
                                             nx_, nt_);
    }
    // w_feat softmax -> split-bf16 w2
    k_softmax_w2<<<B_ROWS, 256, 0, stream>>>(S, w2);
    // asf transpose+split into S region (S dead)
    {
        dim3 g(NT / 64, DIM / 64);
        k_conv2t<<<g, 256, 0, stream>>>(asf, asfT2);
    }
    // G2: parts[z] = w2 @ asfT2^T  (M=1024, N=1024, K=8192, split-K x8)
    {
        dim3 g(DIM / 128, B_ROWS / 128, 8);
        k_gemm3<false><<<g, 256, 0, stream>>>(w2, asfT2, parts, B_ROWS, DIM, NT, NT / 8,
                                              nullptr, nullptr);
    }
    // fused: reduce8 + xsrc fp32 + hi/lo split + norm
    k_fuse_xsrc<<<B_ROWS, 256, 0, stream>>>(parts, xsrc, xsrc2, nx2_);
    k_preds<<<B_ROWS, 64, 0, stream>>>(xsrc, W, bias, preds);
    // sf conversion + norm (parts dead)
    k_conv_norm<<<NS, 256, 0, stream>>>(sf, sf2, ns_);

    // G3: S = logits(-TEMP*d(xsrc, sf))  (M=1024, N=8192, K=1024)
    {
        dim3 g(NS / 128, B_ROWS / 128, 1);
        k_gemm3<true><<<g, 256, 0, stream>>>(xsrc2, sf2, S, B_ROWS, NS, DIM, DIM,
                                             nx2_, ns_);
    }
    // label softmax (with M2T term) + y, 2 rows/block
    k_lab_softmax_y<<<B_ROWS / 2, 256, 0, stream>>>(S, preds, M2Tt, atlt, y);
}

// Round 7
// 341.439 us; speedup vs baseline: 3.4480x; 1.0120x over previous
//
#include <hip/hip_runtime.h>
#include <hip/hip_bf16.h>
#include <math.h>

#define B_ROWS 1024
#define NT 8192
#define NS 8192
#define DIM 1024
#define NC 10
#define TEMP 100.0f

typedef __bf16 bf16x8 __attribute__((ext_vector_type(8)));
typedef __bf16 bf16x4 __attribute__((ext_vector_type(4)));
typedef float f32x4 __attribute__((ext_vector_type(4)));

#define GLOAD_LDS(g, l) \
    __builtin_amdgcn_global_load_lds((__attribute__((address_space(1))) void*)(g), \
                                     (__attribute__((address_space(3))) void*)(l), 16, 0, 0)

__device__ inline __bf16 split_hi(float v) { return (__bf16)v; }
__device__ inline __bf16 split_lo(float v) {
    __bf16 h = (__bf16)v;
    return (__bf16)(v - (float)h);
}

// ---------------- reduction helpers ----------------
__device__ inline float wave_max(float v) {
    #pragma unroll
    for (int off = 32; off > 0; off >>= 1)
        v = fmaxf(v, __shfl_down(v, off, 64));
    return v;
}
__device__ inline float wave_sum(float v) {
    #pragma unroll
    for (int off = 32; off > 0; off >>= 1)
        v += __shfl_down(v, off, 64);
    return v;
}

// ---------------- fused fp32->bf16 hi/lo split + row norm (rows of 1024) -----
__global__ __launch_bounds__(256) void k_conv_norm(const float* __restrict__ X,
                                                   __bf16* __restrict__ X2,
                                                   float* __restrict__ norms) {
    int row = blockIdx.x;
    int c = threadIdx.x * 4;
    float4 v = *(const float4*)(X + (size_t)row * DIM + c);
    bf16x4 h, l;
    h[0] = split_hi(v.x); l[0] = split_lo(v.x);
    h[1] = split_hi(v.y); l[1] = split_lo(v.y);
    h[2] = split_hi(v.z); l[2] = split_lo(v.z);
    h[3] = split_hi(v.w); l[3] = split_lo(v.w);
    *(bf16x4*)(X2 + (size_t)row * 2048 + c) = h;
    *(bf16x4*)(X2 + (size_t)row * 2048 + 1024 + c) = l;
    float acc = v.x * v.x + v.y * v.y + v.z * v.z + v.w * v.w;
    __shared__ float s[4];
    float w = wave_sum(acc);
    int lane = threadIdx.x & 63, wid = threadIdx.x >> 6;
    if (lane == 0) s[wid] = w;
    __syncthreads();
    if (threadIdx.x == 0) norms[row] = s[0] + s[1] + s[2] + s[3];
}

// ---------------- asf [8192][1024] -> transposed hi/lo split [1024][2*8192] ----
__global__ __launch_bounds__(256) void k_conv2t(const float* __restrict__ X,
                                                __bf16* __restrict__ XT2) {
    __shared__ float t[64][65];
    int k0 = blockIdx.x * 64;  // source row block (k dim, 8192)
    int n0 = blockIdx.y * 64;  // source col block (n dim, 1024)
    int tid = threadIdx.x;
    int tr = tid >> 4;          // 0..15
    int tc = (tid & 15) * 4;    // 0..60
    #pragma unroll
    for (int i = 0; i < 4; i++) {
        int r = tr + i * 16;
        float4 v = *(const float4*)(X + (size_t)(k0 + r) * 1024 + n0 + tc);
        t[r][tc] = v.x; t[r][tc + 1] = v.y; t[r][tc + 2] = v.z; t[r][tc + 3] = v.w;
    }
    __syncthreads();
    #pragma unroll
    for (int i = 0; i < 4; i++) {
        int n = tr + i * 16;   // output row (n), local
        bf16x4 h, l;
        #pragma unroll
        for (int e = 0; e < 4; e++) {
            float v = t[tc + e][n];
            h[e] = split_hi(v);
            l[e] = split_lo(v);
        }
        size_t base = (size_t)(n0 + n) * 16384 + k0 + tc;
        *(bf16x4*)(XT2 + base) = h;
        *(bf16x4*)(XT2 + base + 8192) = l;
    }
}

// ---------------- 3-term split-bf16 MFMA GEMM: C = A*B^T ----------------
// LOGITS=false: plain fp32 C write (+ blockIdx.z * M*N partials)
// LOGITS=true:  write logits  -TEMP*sqrt(rowN+colN-2*dot)
// 128x128 tile, BK=64; LDS row = 128B bank period; chunk XOR (row&7) conflict-free
// Block swizzle: XCD = linear_id % 8 (round-robin). Map so the 8 row-blocks
// sharing a B-tile land on one XCD concurrently (B fetched ~once/XCD; A is L2-resident).
template <bool LOGITS>
__global__ __launch_bounds__(256) void k_gemm3(const __bf16* __restrict__ A2,
                                               const __bf16* __restrict__ B2,
                                               float* __restrict__ C,
                                               int M, int N, int K, int ksplit,
                                               const float* __restrict__ rowN,
                                               const float* __restrict__ colN) {
    __shared__ unsigned short AhS[8192], AlS[8192], BhS[8192], BlS[8192]; // 128x64 each
    __shared__ float extraL[LOGITS ? 256 : 2];
    float* rnL = extraL;                    // [128]
    float* cnL = extraL + 128;              // [128]

    int tid = threadIdx.x;
    int wid = tid >> 6, lane = tid & 63;
    int wm = (wid >> 1) * 64, wn = (wid & 1) * 64;
    // swizzle (requires gridDim.y == 8, i.e. M == 1024)
    int id = blockIdx.y * gridDim.x + blockIdx.x;
    int bn_i = ((id >> 6) << 3) | (id & 7);
    int bm_i = (id >> 3) & 7;
    int bm = bm_i * 128, bn = bn_i * 128;
    size_t K2 = 2 * (size_t)K;
    int k_begin = blockIdx.z * ksplit;
    int nsteps = ksplit >> 6;

    if (LOGITS) {
        if (tid < 128) rnL[tid] = rowN[bm + tid];
        else cnL[tid - 128] = colN[bn + tid - 128];
    }

    f32x4 acc[4][4];
    #pragma unroll
    for (int i = 0; i < 4; i++)
        #pragma unroll
        for (int j = 0; j < 4; j++) acc[i][j] = (f32x4){0.f, 0.f, 0.f, 0.f};

    // staging: wave wid covers rows [wid*32, wid*32+32), 4 glds passes of 8 rows
    int r_in = lane >> 3;                    // 0..7 row within 8-row pass
    int cgo = ((lane & 7) ^ r_in) * 8;       // swizzled chunk (element offset)
    const __bf16* gA = A2 + (size_t)(bm + wid * 32 + r_in) * K2 + k_begin + cgo;
    const __bf16* gB = B2 + (size_t)(bn + wid * 32 + r_in) * K2 + k_begin + cgo;
    char* AhB = (char*)AhS; char* AlB = (char*)AlS;
    char* BhB = (char*)BhS; char* BlB = (char*)BlS;
    int lbw = wid * 4096;
    size_t row8 = 8 * K2;

    // fragment read offsets (elements), swizzle-compensated
    int ra = lane & 15, q = lane >> 4;
    int aoff[4][2], boff[4][2];
    #pragma unroll
    for (int i = 0; i < 4; i++) {
        #pragma unroll
        for (int kh = 0; kh < 2; kh++) {
            int chunk = ((kh << 2) | q) ^ (ra & 7);
            aoff[i][kh] = (wm + i * 16 + ra) * 64 + chunk * 8;
            boff[i][kh] = (wn + i * 16 + ra) * 64 + chunk * 8;
        }
    }
    const __bf16* AhE = (const __bf16*)AhS;
    const __bf16* AlE = (const __bf16*)AlS;
    const __bf16* BhE = (const __bf16*)BhS;
    const __bf16* BlE = (const __bf16*)BlS;

    for (int ks = 0; ks < nsteps; ks++) {
        __syncthreads();
        #pragma unroll
        for (int p = 0; p < 4; p++) {
            size_t go = p * row8;
            int lo = lbw + p * 1024;
            GLOAD_LDS(gA + go, AhB + lo);
            GLOAD_LDS(gA + go + K, AlB + lo);
            GLOAD_LDS(gB + go, BhB + lo);
            GLOAD_LDS(gB + go + K, BlB + lo);
        }
        gA += 64; gB += 64;
        __syncthreads();

        #pragma unroll
        for (int kh = 0; kh < 2; kh++) {
            bf16x8 ah[4], al[4];
            #pragma unroll
            for (int mi = 0; mi < 4; mi++) {
                ah[mi] = *(const bf16x8*)(AhE + aoff[mi][kh]);
                al[mi] = *(const bf16x8*)(AlE + aoff[mi][kh]);
            }
            #pragma unroll
            for (int ni = 0; ni < 4; ni++) {
                bf16x8 bh = *(const bf16x8*)(BhE + boff[ni][kh]);
                bf16x8 bl = *(const bf16x8*)(BlE + boff[ni][kh]);
                #pragma unroll
                for (int mi = 0; mi < 4; mi++) {
                    acc[mi][ni] = __builtin_amdgcn_mfma_f32_16x16x32_bf16(ah[mi], bh, acc[mi][ni], 0, 0, 0);
                    acc[mi][ni] = __builtin_amdgcn_mfma_f32_16x16x32_bf16(ah[mi], bl, acc[mi][ni], 0, 0, 0);
                    acc[mi][ni] = __builtin_amdgcn_mfma_f32_16x16x32_bf16(al[mi], bh, acc[mi][ni], 0, 0, 0);
                }
            }
        }
    }

    if (!LOGITS) {
        float* Cb = C + (size_t)blockIdx.z * M * N;
        #pragma unroll
        for (int mi = 0; mi < 4; mi++) {
            #pragma unroll
            for (int ni = 0; ni < 4; ni++) {
                int r0 = bm + wm + mi * 16 + q * 4;
                int c0 = bn + wn + ni * 16 + ra;
                Cb[(size_t)(r0 + 0) * N + c0] = acc[mi][ni][0];
                Cb[(size_t)(r0 + 1) * N + c0] = acc[mi][ni][1];
                Cb[(size_t)(r0 + 2) * N + c0] = acc[mi][ni][2];
                Cb[(size_t)(r0 + 3) * N + c0] = acc[mi][ni][3];
            }
        }
    } else {
        #pragma unroll
        for (int mi = 0; mi < 4; mi++) {
            #pragma unroll
            for (int ni = 0; ni < 4; ni++) {
                int cl = wn + ni * 16 + ra;
                float cn = cnL[cl];
                #pragma unroll
                for (int i = 0; i < 4; i++) {
                    int rl = wm + mi * 16 + q * 4 + i;
                    float sq = rnL[rl] + cn - 2.f * acc[mi][ni][i];
                    float d = sqrtf(fmaxf(sq, 1e-12f));
                    C[(size_t)(bm + rl) * N + bn + cl] = -TEMP * d;
                }
            }
        }
    }
}

// -- fused: sum 8 split-K partials + hi/lo split + norm + classifier preds ----
__global__ __launch_bounds__(256) void k_fuse_xsrc(const float* __restrict__ parts,
                                                   const float* __restrict__ W,
                                                   const float* __restrict__ bias,
                                                   __bf16* __restrict__ xsrc2,
                                                   float* __restrict__ norms,
                                                   float* __restrict__ preds) {
    int row = blockIdx.x;
    int c = threadIdx.x * 4;
    size_t off = (size_t)row * DIM + c;
    float4 s = make_float4(0.f, 0.f, 0.f, 0.f);
    #pragma unroll
    for (int z = 0; z < 8; z++) {
        float4 v = *(const float4*)(parts + (size_t)z * (B_ROWS * DIM) + off);
        s.x += v.x; s.y += v.y; s.z += v.z; s.w += v.w;
    }
    bf16x4 h, l;
    h[0] = split_hi(s.x); l[0] = split_lo(s.x);
    h[1] = split_hi(s.y); l[1] = split_lo(s.y);
    h[2] = split_hi(s.z); l[2] = split_lo(s.z);
    h[3] = split_hi(s.w); l[3] = split_lo(s.w);
    *(bf16x4*)(xsrc2 + (size_t)row * 2048 + c) = h;
    *(bf16x4*)(xsrc2 + (size_t)row * 2048 + 1024 + c) = l;
    float accn = s.x * s.x + s.y * s.y + s.z * s.z + s.w * s.w;
    float accp[NC];
    #pragma unroll
    for (int cc = 0; cc < NC; cc++)
        accp[cc] = s.x * W[(c + 0) * NC + cc] + s.y * W[(c + 1) * NC + cc]
                 + s.z * W[(c + 2) * NC + cc] + s.w * W[(c + 3) * NC + cc];
    __shared__ float red[4][NC + 1];
    accn = wave_sum(accn);
    #pragma unroll
    for (int cc = 0; cc < NC; cc++) accp[cc] = wave_sum(accp[cc]);
    int lane = threadIdx.x & 63, wid = threadIdx.x >> 6;
    if (lane == 0) {
        red[wid][0] = accn;
        #pragma unroll
        for (int cc = 0; cc < NC; cc++) red[wid][1 + cc] = accp[cc];
    }
    __syncthreads();
    if (threadIdx.x == 0) {
        norms[row] = red[0][0] + red[1][0] + red[2][0] + red[3][0];
        float lo[NC];
        float m = -1e30f;
        #pragma unroll
        for (int cc = 0; cc < NC; cc++) {
            lo[cc] = red[0][1 + cc] + red[1][1 + cc] + red[2][1 + cc] + red[3][1 + cc]
                   + bias[cc];
            m = fmaxf(m, lo[cc]);
        }
        float ssum = 0.f;
        #pragma unroll
        for (int cc = 0; cc < NC; cc++) {
            lo[cc] = __expf(lo[cc] - m);
            ssum += lo[cc];
        }
        float inv = 1.0f / ssum;
        #pragma unroll
        for (int cc = 0; cc < NC; cc++) preds[(size_t)row * NC + cc] = lo[cc] * inv;
    }
}

// ---------------- feature softmax (input = logits) -> split-bf16 w ------------
__global__ __launch_bounds__(256) void k_softmax_w2(const float* __restrict__ S,
                                                    __bf16* __restrict__ w2) {
    int row = blockIdx.x;
    const float* sr = S + (size_t)row * NT;
    float vals[NT / 256];
    float lmax = -1e30f;
    #pragma unroll
    for (int u = 0; u < NT / 256; u++) {
        int j = threadIdx.x + u * 256;
        float l = sr[j];
        vals[u] = l;
        lmax = fmaxf(lmax, l);
    }
    __shared__ float sm[4];
    __shared__ float ss[4];
    int lane = threadIdx.x & 63, wid = threadIdx.x >> 6;
    float wm = wave_max(lmax);
    if (lane == 0) sm[wid] = wm;
    __syncthreads();
    float bmax = fmaxf(fmaxf(sm[0], sm[1]), fmaxf(sm[2], sm[3]));
    float lsum = 0.f;
    #pragma unroll
    for (int u = 0; u < NT / 256; u++) {
        float e = __expf(vals[u] - bmax);
        vals[u] = e;
        lsum += e;
    }
    float wsumv = wave_sum(lsum);
    if (lane == 0) ss[wid] = wsumv;
    __syncthreads();
    float bsum = ss[0] + ss[1] + ss[2] + ss[3];
    float inv = 1.0f / bsum;
    __bf16* wr = w2 + (size_t)row * 16384;
    #pragma unroll
    for (int u = 0; u < NT / 256; u++) {
        int j = threadIdx.x + u * 256;
        float w = vals[u] * inv;
        wr[j] = split_hi(w);
        wr[8192 + j] = split_lo(w);
    }
}

// ------- prep: M2Tt[c][j] = sum_k sld[c][k]*shdl[j][k];  atlt[c][j] = atl[j][c]
__global__ __launch_bounds__(256) void k_prep_labels(const float* __restrict__ sld,
                                                     const float* __restrict__ shdl,
                                                     const float* __restrict__ atl,
                                                     float* __restrict__ M2Tt,
                                                     float* __restrict__ atlt) {
    __shared__ float sldL[NC * NC];
    if (threadIdx.x < NC * NC) sldL[threadIdx.x] = sld[threadIdx.x];
    __syncthreads();
    int j = blockIdx.x * 256 + threadIdx.x;
    float sh[NC], at[NC];
    #pragma unroll
    for (int k = 0; k < NC; k++) sh[k] = shdl[(size_t)j * NC + k];
    #pragma unroll
    for (int c = 0; c < NC; c++) at[c] = atl[(size_t)j * NC + c];
    #pragma unroll
    for (int c = 0; c < NC; c++) {
        float t = 0.f;
        #pragma unroll
        for (int k = 0; k < NC; k++) t += sldL[c * NC + k] * sh[k];
        M2Tt[c * NS + j] = t;
        atlt[c * NS + j] = at[c];
    }
}

// ------- label softmax + y, 2 rows per block ---------------------------------
// logits = S[row][j] - TEMP * sum_c preds[row][c]*M2Tt[c][j]
__global__ __launch_bounds__(256) void k_lab_softmax_y(const float* __restrict__ S,
                                                       const float* __restrict__ predsG,
                                                       const float* __restrict__ M2Tt,
                                                       const float* __restrict__ atlt,
                                                       float* __restrict__ y) {
    int r0 = blockIdx.x * 2, r1 = r0 + 1;
    float pr0[NC], pr1[NC];
    #pragma unroll
    for (int c = 0; c < NC; c++) {
        pr0[c] = predsG[(size_t)r0 * NC + c];
        pr1[c] = predsG[(size_t)r1 * NC + c];
    }
    const float* s0 = S + (size_t)r0 * NS;
    const float* s1 = S + (size_t)r1 * NS;
    float v0[NS / 256], v1[NS / 256];
    float m0 = -1e30f, m1 = -1e30f;
    #pragma unroll
    for (int u = 0; u < NS / 256; u++) {
        int j = threadIdx.x + u * 256;
        float lab0 = 0.f, lab1 = 0.f;
        #pragma unroll
        for (int c = 0; c < NC; c++) {
            float mv = M2Tt[c * NS + j];
            lab0 += pr0[c] * mv;
            lab1 += pr1[c] * mv;
        }
        float l0 = s0[j] - TEMP * lab0;
        float l1 = s1[j] - TEMP * lab1;
        v0[u] = l0; v1[u] = l1;
        m0 = fmaxf(m0, l0); m1 = fmaxf(m1, l1);
    }
    __shared__ float sm[2][4];
    __shared__ float ss[2][4];
    __shared__ float yred[4][2][NC];
    int lane = threadIdx.x & 63, wid = threadIdx.x >> 6;
    float wm0 = wave_max(m0), wm1 = wave_max(m1);
    if (lane == 0) { sm[0][wid] = wm0; sm[1][wid] = wm1; }
    __syncthreads();
    float bm0 = fmaxf(fmaxf(sm[0][0], sm[0][1]), fmaxf(sm[0][2], sm[0][3]));
    float bm1 = fmaxf(fmaxf(sm[1][0], sm[1][1]), fmaxf(sm[1][2], sm[1][3]));
    float ls0 = 0.f, ls1 = 0.f;
    #pragma unroll
    for (int u = 0; u < NS / 256; u++) {
        float e0 = __expf(v0[u] - bm0);
        float e1 = __expf(v1[u] - bm1);
        v0[u] = e0; v1[u] = e1;
        ls0 += e0; ls1 += e1;
    }
    float ws0 = wave_sum(ls0), ws1 = wave_sum(ls1);
    if (lane == 0) { ss[0][wid] = ws0; ss[1][wid] = ws1; }
    __syncthreads();
    float inv0 = 1.0f / (ss[0][0] + ss[0][1] + ss[0][2] + ss[0][3]);
    float inv1 = 1.0f / (ss[1][0] + ss[1][1] + ss[1][2] + ss[1][3]);
    float y0[NC] = {}, y1[NC] = {};
    #pragma unroll
    for (int u = 0; u < NS / 256; u++) {
        int j = threadIdx.x + u * 256;
        float w0 = v0[u] * inv0;
        float w1 = v1[u] * inv1;
        #pragma unroll
        for (int c = 0; c < NC; c++) {
            float av = atlt[c * NS + j];
            y0[c] += w0 * av;
            y1[c] += w1 * av;
        }
    }
    #pragma unroll
    for (int c = 0; c < NC; c++) { y0[c] = wave_sum(y0[c]); y1[c] = wave_sum(y1[c]); }
    if (lane == 0) {
        #pragma unroll
        for (int c = 0; c < NC; c++) { yred[wid][0][c] = y0[c]; yred[wid][1][c] = y1[c]; }
    }
    __syncthreads();
    if (threadIdx.x < 2 * NC) {
        int r = threadIdx.x / NC, c = threadIdx.x - r * NC;
        y[(size_t)(r0 + r) * NC + c] = yred[0][r][c] + yred[1][r][c] + yred[2][r][c] + yred[3][r][c];
    }
}

extern "C" void kernel_launch(void* const* d_in, const int* in_sizes, int n_in,
                              void* d_out, int out_size, void* d_ws, size_t ws_size,
                              hipStream_t stream) {
    const float* x    = (const float*)d_in[0];   // [1024, 32, 32]
    const float* tf   = (const float*)d_in[1];   // [8192, 1024]
    const float* asf  = (const float*)d_in[2];   // [8192, 1024]
    const float* sf   = (const float*)d_in[3];   // [8192, 1024]
    const float* shdl = (const float*)d_in[4];   // [8192, 10]
    const float* atl  = (const float*)d_in[5];   // [8192, 10]
    const float* sld  = (const float*)d_in[6];   // [10, 10]
    const float* W    = (const float*)d_in[7];   // [1024, 10]
    const float* bias = (const float*)d_in[8];   // [10]
    float* y = (float*)d_out;                    // [1024, 10]

    char* wsb = (char*)d_ws;
    float*  S     = (float*)(wsb);                          // 32 MiB; aliased by asfT2
    __bf16* asfT2 = (__bf16*)S;                             // [1024][16384]
    float*  BIG1  = (float*)(wsb + (32u << 20));            // 32 MiB: tf2 -> parts -> sf2
    __bf16* tf2   = (__bf16*)BIG1;
    float*  parts = BIG1;                                   // 8 x 4 MiB split-K partials
    __bf16* sf2   = (__bf16*)BIG1;
    __bf16* w2    = (__bf16*)(wsb + (64u << 20));           // 32 MiB
    __bf16* x2    = (__bf16*)(wsb + (96u << 20));           // 4 MiB
    __bf16* xsrc2 = (__bf16*)(wsb + (100u << 20));          // 4 MiB
    float*  nt_   = (float*)(wsb + (108u << 20));
    float*  ns_   = nt_ + NT;
    float*  nx_   = ns_ + NS;
    float*  nx2_  = nx_ + B_ROWS;
    float*  preds = nx2_ + B_ROWS;
    float*  M2Tt  = preds + B_ROWS * NC;                    // [10][8192]
    float*  atlt  = M2Tt + NS * NC;                         // [10][8192]

    // fused conversions + norms; label matrices (transposed)
    k_conv_norm<<<B_ROWS, 256, 0, stream>>>(x, x2, nx_);
    k_conv_norm<<<NT, 256, 0, stream>>>(tf, tf2, nt_);
    k_prep_labels<<<NS / 256, 256, 0, stream>>>(sld, shdl, atl, M2Tt, atlt);

    // G1: S = logits(-TEMP*d(x, tf))   (M=1024, N=8192, K=1024)
    {
        dim3 g(NT / 128, B_ROWS / 128, 1);
        k_gemm3<true><<<g, 256, 0, stream>>>(x2, tf2, S, B_ROWS, NT, DIM, DIM,
                                             nx_, nt_);
    }
    // w_feat softmax -> split-bf16 w2
    k_softmax_w2<<<B_ROWS, 256, 0, stream>>>(S, w2);
    // asf transpose+split into S region (S dead)
    {
        dim3 g(NT / 64, DIM / 64);
        k_conv2t<<<g, 256, 0, stream>>>(asf, asfT2);
    }
    // G2: parts[z] = w2 @ asfT2^T  (M=1024, N=1024, K=8192, split-K x8)
    {
        dim3 g(DIM / 128, B_ROWS / 128, 8);
        k_gemm3<false><<<g, 256, 0, stream>>>(w2, asfT2, parts, B_ROWS, DIM, NT, NT / 8,
                                              nullptr, nullptr);
    }
    // fused: reduce8 + hi/lo split + norm + preds
    k_fuse_xsrc<<<B_ROWS, 256, 0, stream>>>(parts, W, bias, xsrc2, nx2_, preds);
    // sf conversion + norm (parts dead)
    k_conv_norm<<<NS, 256, 0, stream>>>(sf, sf2, ns_);

    // G3: S = logits(-TEMP*d(xsrc, sf))  (M=1024, N=8192, K=1024)
    {
        dim3 g(NS / 128, B_ROWS / 128, 1);
        k_gemm3<true><<<g, 256, 0, stream>>>(xsrc2, sf2, S, B_ROWS, NS, DIM, DIM,
                                             nx2_, ns_);
    }
    // label softmax (with M2T term) + y, 2 rows/block
    k_lab_softmax_y<<<B_ROWS / 2, 256, 0, stream>>>(S, preds, M2Tt, atlt, y);
}

// Round 9
// 335.793 us; speedup vs baseline: 3.5059x; 1.0168x over previous
//
#include <hip/hip_runtime.h>
#include <hip/hip_bf16.h>
#include <math.h>

#define B_ROWS 1024
#define NT 8192
#define NS 8192
#define DIM 1024
#define NC 10
#define TEMP 100.0f

typedef __bf16 bf16x8 __attribute__((ext_vector_type(8)));
typedef __bf16 bf16x4 __attribute__((ext_vector_type(4)));
typedef float f32x4 __attribute__((ext_vector_type(4)));

#define GLOAD_LDS(g, l) \
    __builtin_amdgcn_global_load_lds((__attribute__((address_space(1))) void*)(g), \
                                     (__attribute__((address_space(3))) void*)(l), 16, 0, 0)

__device__ inline __bf16 split_hi(float v) { return (__bf16)v; }
__device__ inline __bf16 split_lo(float v) {
    __bf16 h = (__bf16)v;
    return (__bf16)(v - (float)h);
}

// ---------------- reduction helpers ----------------
__device__ inline float wave_max(float v) {
    #pragma unroll
    for (int off = 32; off > 0; off >>= 1)
        v = fmaxf(v, __shfl_down(v, off, 64));
    return v;
}
__device__ inline float wave_sum(float v) {
    #pragma unroll
    for (int off = 32; off > 0; off >>= 1)
        v += __shfl_down(v, off, 64);
    return v;
}

// ---- device helper: fp32 row (1024) -> bf16 hi/lo split + row norm ----------
__device__ inline void conv_norm_row(const float* __restrict__ X, int row,
                                     __bf16* __restrict__ X2,
                                     float* __restrict__ norms,
                                     float* sred) {
    int c = threadIdx.x * 4;
    float4 v = *(const float4*)(X + (size_t)row * DIM + c);
    bf16x4 h, l;
    h[0] = split_hi(v.x); l[0] = split_lo(v.x);
    h[1] = split_hi(v.y); l[1] = split_lo(v.y);
    h[2] = split_hi(v.z); l[2] = split_lo(v.z);
    h[3] = split_hi(v.w); l[3] = split_lo(v.w);
    *(bf16x4*)(X2 + (size_t)row * 2048 + c) = h;
    *(bf16x4*)(X2 + (size_t)row * 2048 + 1024 + c) = l;
    float acc = v.x * v.x + v.y * v.y + v.z * v.z + v.w * v.w;
    float w = wave_sum(acc);
    int lane = threadIdx.x & 63, wid = threadIdx.x >> 6;
    if (lane == 0) sred[wid] = w;
    __syncthreads();
    if (threadIdx.x == 0) norms[row] = sred[0] + sred[1] + sred[2] + sred[3];
}

// ---- K0: conv_norm(x) [0,1024) + conv_norm(tf) [1024,9216) + prep_labels ----
__global__ __launch_bounds__(256) void k_prep0(const float* __restrict__ x,
                                               const float* __restrict__ tf,
                                               const float* __restrict__ sld,
                                               const float* __restrict__ shdl,
                                               const float* __restrict__ atl,
                                               __bf16* __restrict__ x2,
                                               __bf16* __restrict__ tf2,
                                               float* __restrict__ nx_,
                                               float* __restrict__ nt_,
                                               float* __restrict__ M2Tt,
                                               float* __restrict__ atlt) {
    __shared__ float sred[4];
    __shared__ float sldL[NC * NC];
    int b = blockIdx.x;
    if (b < B_ROWS) {
        conv_norm_row(x, b, x2, nx_, sred);
    } else if (b < B_ROWS + NT) {
        conv_norm_row(tf, b - B_ROWS, tf2, nt_, sred);
    } else {
        if (threadIdx.x < NC * NC) sldL[threadIdx.x] = sld[threadIdx.x];
        __syncthreads();
        int j = (b - B_ROWS - NT) * 256 + threadIdx.x;
        float sh[NC], at[NC];
        #pragma unroll
        for (int k = 0; k < NC; k++) sh[k] = shdl[(size_t)j * NC + k];
        #pragma unroll
        for (int c = 0; c < NC; c++) at[c] = atl[(size_t)j * NC + c];
        #pragma unroll
        for (int c = 0; c < NC; c++) {
            float t = 0.f;
            #pragma unroll
            for (int k = 0; k < NC; k++) t += sldL[c * NC + k] * sh[k];
            M2Tt[c * NS + j] = t;
            atlt[c * NS + j] = at[c];
        }
    }
}

// ---- conv2t(asf): [8192][1024] -> transposed hi/lo split [1024][2*8192] -----
__global__ __launch_bounds__(256) void k_conv2t(const float* __restrict__ asf,
                                                __bf16* __restrict__ asfT2) {
    __shared__ float t[64][65];
    int b = blockIdx.x;
    int k0 = (b >> 4) * 64;          // source row block (k dim, 8192)
    int n0 = (b & 15) * 64;          // source col block (n dim, 1024)
    int tid = threadIdx.x;
    int tr = tid >> 4;               // 0..15
    int tc = (tid & 15) * 4;         // 0..60
    #pragma unroll
    for (int i = 0; i < 4; i++) {
        int r = tr + i * 16;
        float4 v = *(const float4*)(asf + (size_t)(k0 + r) * 1024 + n0 + tc);
        t[r][tc] = v.x; t[r][tc + 1] = v.y; t[r][tc + 2] = v.z; t[r][tc + 3] = v.w;
    }
    __syncthreads();
    #pragma unroll
    for (int i = 0; i < 4; i++) {
        int n = tr + i * 16;
        bf16x4 h, l;
        #pragma unroll
        for (int e = 0; e < 4; e++) {
            float v = t[tc + e][n];
            h[e] = split_hi(v);
            l[e] = split_lo(v);
        }
        size_t base = (size_t)(n0 + n) * 16384 + k0 + tc;
        *(bf16x4*)(asfT2 + base) = h;
        *(bf16x4*)(asfT2 + base + 8192) = l;
    }
}

// ---------------- 3-term split-bf16 MFMA GEMM: C = A*B^T ----------------
// LOGITS=false: plain fp32 C write (+ blockIdx.z * M*N partials)
// LOGITS=true:  write logits  -TEMP*sqrt(rowN+colN-2*dot)
// 128x128 tile, BK=64; LDS row = 128B bank period; chunk XOR (row&7) conflict-free
template <bool LOGITS>
__global__ __launch_bounds__(256) void k_gemm3(const __bf16* __restrict__ A2,
                                               const __bf16* __restrict__ B2,
                                               float* __restrict__ C,
                                               int M, int N, int K, int ksplit,
                                               const float* __restrict__ rowN,
                                               const float* __restrict__ colN) {
    __shared__ unsigned short AhS[8192], AlS[8192], BhS[8192], BlS[8192]; // 128x64 each
    __shared__ float extraL[LOGITS ? 256 : 2];
    float* rnL = extraL;
    float* cnL = extraL + 128;

    int tid = threadIdx.x;
    int wid = tid >> 6, lane = tid & 63;
    int wm = (wid >> 1) * 64, wn = (wid & 1) * 64;
    int id = blockIdx.y * gridDim.x + blockIdx.x;
    int bn_i = ((id >> 6) << 3) | (id & 7);
    int bm_i = (id >> 3) & 7;
    int bm = bm_i * 128, bn = bn_i * 128;
    size_t K2 = 2 * (size_t)K;
    int k_begin = blockIdx.z * ksplit;
    int nsteps = ksplit >> 6;

    if (LOGITS) {
        if (tid < 128) rnL[tid] = rowN[bm + tid];
        else cnL[tid - 128] = colN[bn + tid - 128];
    }

    f32x4 acc[4][4];
    #pragma unroll
    for (int i = 0; i < 4; i++)
        #pragma unroll
        for (int j = 0; j < 4; j++) acc[i][j] = (f32x4){0.f, 0.f, 0.f, 0.f};

    int r_in = lane >> 3;
    int cgo = ((lane & 7) ^ r_in) * 8;
    const __bf16* gA = A2 + (size_t)(bm + wid * 32 + r_in) * K2 + k_begin + cgo;
    const __bf16* gB = B2 + (size_t)(bn + wid * 32 + r_in) * K2 + k_begin + cgo;
    char* AhB = (char*)AhS; char* AlB = (char*)AlS;
    char* BhB = (char*)BhS; char* BlB = (char*)BlS;
    int lbw = wid * 4096;
    size_t row8 = 8 * K2;

    int ra = lane & 15, q = lane >> 4;
    int aoff[4][2], boff[4][2];
    #pragma unroll
    for (int i = 0; i < 4; i++) {
        #pragma unroll
        for (int kh = 0; kh < 2; kh++) {
            int chunk = ((kh << 2) | q) ^ (ra & 7);
            aoff[i][kh] = (wm + i * 16 + ra) * 64 + chunk * 8;
            boff[i][kh] = (wn + i * 16 + ra) * 64 + chunk * 8;
        }
    }
    const __bf16* AhE = (const __bf16*)AhS;
    const __bf16* AlE = (const __bf16*)AlS;
    const __bf16* BhE = (const __bf16*)BhS;
    const __bf16* BlE = (const __bf16*)BlS;

    for (int ks = 0; ks < nsteps; ks++) {
        __syncthreads();
        #pragma unroll
        for (int p = 0; p < 4; p++) {
            size_t go = p * row8;
            int lo = lbw + p * 1024;
            GLOAD_LDS(gA + go, AhB + lo);
            GLOAD_LDS(gA + go + K, AlB + lo);
            GLOAD_LDS(gB + go, BhB + lo);
            GLOAD_LDS(gB + go + K, BlB + lo);
        }
        gA += 64; gB += 64;
        __syncthreads();

        #pragma unroll
        for (int kh = 0; kh < 2; kh++) {
            bf16x8 ah[4], al[4];
            #pragma unroll
            for (int mi = 0; mi < 4; mi++) {
                ah[mi] = *(const bf16x8*)(AhE + aoff[mi][kh]);
                al[mi] = *(const bf16x8*)(AlE + aoff[mi][kh]);
            }
            #pragma unroll
            for (int ni = 0; ni < 4; ni++) {
                bf16x8 bh = *(const bf16x8*)(BhE + boff[ni][kh]);
                bf16x8 bl = *(const bf16x8*)(BlE + boff[ni][kh]);
                #pragma unroll
                for (int mi = 0; mi < 4; mi++) {
                    acc[mi][ni] = __builtin_amdgcn_mfma_f32_16x16x32_bf16(ah[mi], bh, acc[mi][ni], 0, 0, 0);
                    acc[mi][ni] = __builtin_amdgcn_mfma_f32_16x16x32_bf16(ah[mi], bl, acc[mi][ni], 0, 0, 0);
                    acc[mi][ni] = __builtin_amdgcn_mfma_f32_16x16x32_bf16(al[mi], bh, acc[mi][ni], 0, 0, 0);
                }
            }
        }
    }

    if (!LOGITS) {
        float* Cb = C + (size_t)blockIdx.z * M * N;
        #pragma unroll
        for (int mi = 0; mi < 4; mi++) {
            #pragma unroll
            for (int ni = 0; ni < 4; ni++) {
                int r0 = bm + wm + mi * 16 + q * 4;
                int c0 = bn + wn + ni * 16 + ra;
                Cb[(size_t)(r0 + 0) * N + c0] = acc[mi][ni][0];
                Cb[(size_t)(r0 + 1) * N + c0] = acc[mi][ni][1];
                Cb[(size_t)(r0 + 2) * N + c0] = acc[mi][ni][2];
                Cb[(size_t)(r0 + 3) * N + c0] = acc[mi][ni][3];
            }
        }
    } else {
        #pragma unroll
        for (int mi = 0; mi < 4; mi++) {
            #pragma unroll
            for (int ni = 0; ni < 4; ni++) {
                int cl = wn + ni * 16 + ra;
                float cn = cnL[cl];
                #pragma unroll
                for (int i = 0; i < 4; i++) {
                    int rl = wm + mi * 16 + q * 4 + i;
                    float sq = rnL[rl] + cn - 2.f * acc[mi][ni][i];
                    float d = sqrtf(fmaxf(sq, 1e-12f));
                    C[(size_t)(bm + rl) * N + bn + cl] = -TEMP * d;
                }
            }
        }
    }
}

// -- K_fuse2: [0,1024): reduce8 partials + split + norm + preds
//             [1024,9216): conv_norm(sf) -> sf2 (in dead w2 region)
__global__ __launch_bounds__(256) void k_fuse2(const float* __restrict__ parts,
                                               const float* __restrict__ sf,
                                               const float* __restrict__ W,
                                               const float* __restrict__ bias,
                                               __bf16* __restrict__ xsrc2,
                                               __bf16* __restrict__ sf2,
                                               float* __restrict__ nx2_,
                                               float* __restrict__ ns_,
                                               float* __restrict__ preds) {
    __shared__ float red[4][NC + 1];
    __shared__ float sred[4];
    int b = blockIdx.x;
    if (b >= B_ROWS) {
        conv_norm_row(sf, b - B_ROWS, sf2, ns_, sred);
        return;
    }
    int row = b;
    int c = threadIdx.x * 4;
    size_t off = (size_t)row * DIM + c;
    float4 s = make_float4(0.f, 0.f, 0.f, 0.f);
    #pragma unroll
    for (int z = 0; z < 8; z++) {
        float4 v = *(const float4*)(parts + (size_t)z * (B_ROWS * DIM) + off);
        s.x += v.x; s.y += v.y; s.z += v.z; s.w += v.w;
    }
    bf16x4 h, l;
    h[0] = split_hi(s.x); l[0] = split_lo(s.x);
    h[1] = split_hi(s.y); l[1] = split_lo(s.y);
    h[2] = split_hi(s.z); l[2] = split_lo(s.z);
    h[3] = split_hi(s.w); l[3] = split_lo(s.w);
    *(bf16x4*)(xsrc2 + (size_t)row * 2048 + c) = h;
    *(bf16x4*)(xsrc2 + (size_t)row * 2048 + 1024 + c) = l;
    float accn = s.x * s.x + s.y * s.y + s.z * s.z + s.w * s.w;
    float accp[NC];
    #pragma unroll
    for (int cc = 0; cc < NC; cc++)
        accp[cc] = s.x * W[(c + 0) * NC + cc] + s.y * W[(c + 1) * NC + cc]
                 + s.z * W[(c + 2) * NC + cc] + s.w * W[(c + 3) * NC + cc];
    accn = wave_sum(accn);
    #pragma unroll
    for (int cc = 0; cc < NC; cc++) accp[cc] = wave_sum(accp[cc]);
    int lane = threadIdx.x & 63, wid = threadIdx.x >> 6;
    if (lane == 0) {
        red[wid][0] = accn;
        #pragma unroll
        for (int cc = 0; cc < NC; cc++) red[wid][1 + cc] = accp[cc];
    }
    __syncthreads();
    if (threadIdx.x == 0) {
        nx2_[row] = red[0][0] + red[1][0] + red[2][0] + red[3][0];
        float lo[NC];
        float m = -1e30f;
        #pragma unroll
        for (int cc = 0; cc < NC; cc++) {
            lo[cc] = red[0][1 + cc] + red[1][1 + cc] + red[2][1 + cc] + red[3][1 + cc]
                   + bias[cc];
            m = fmaxf(m, lo[cc]);
        }
        float ssum = 0.f;
        #pragma unroll
        for (int cc = 0; cc < NC; cc++) {
            lo[cc] = __expf(lo[cc] - m);
            ssum += lo[cc];
        }
        float inv = 1.0f / ssum;
        #pragma unroll
        for (int cc = 0; cc < NC; cc++) preds[(size_t)row * NC + cc] = lo[cc] * inv;
    }
}

// ------ feature softmax (vectorized float4) -> split-bf16 w ------------------
__global__ __launch_bounds__(256) void k_softmax_w2(const float* __restrict__ S,
                                                    __bf16* __restrict__ w2) {
    int row = blockIdx.x;
    const float4* sr = (const float4*)(S + (size_t)row * NT);   // 2048 float4
    float4 vals[NT / 1024];                                      // 8
    float lmax = -1e30f;
    #pragma unroll
    for (int u = 0; u < NT / 1024; u++) {
        float4 v = sr[threadIdx.x + u * 256];
        vals[u] = v;
        lmax = fmaxf(fmaxf(fmaxf(v.x, v.y), fmaxf(v.z, v.w)), lmax);
    }
    __shared__ float sm[4];
    __shared__ float ss[4];
    int lane = threadIdx.x & 63, wid = threadIdx.x >> 6;
    float wm = wave_max(lmax);
    if (lane == 0) sm[wid] = wm;
    __syncthreads();
    float bmax = fmaxf(fmaxf(sm[0], sm[1]), fmaxf(sm[2], sm[3]));
    float lsum = 0.f;
    #pragma unroll
    for (int u = 0; u < NT / 1024; u++) {
        float4 v = vals[u];
        v.x = __expf(v.x - bmax); v.y = __expf(v.y - bmax);
        v.z = __expf(v.z - bmax); v.w = __expf(v.w - bmax);
        vals[u] = v;
        lsum += v.x + v.y + v.z + v.w;
    }
    float wsumv = wave_sum(lsum);
    if (lane == 0) ss[wid] = wsumv;
    __syncthreads();
    float inv = 1.0f / (ss[0] + ss[1] + ss[2] + ss[3]);
    __bf16* wr = w2 + (size_t)row * 16384;
    #pragma unroll
    for (int u = 0; u < NT / 1024; u++) {
        int j = (threadIdx.x + u * 256) * 4;
        float4 v = vals[u];
        v.x *= inv; v.y *= inv; v.z *= inv; v.w *= inv;
        bf16x4 h, l;
        h[0] = split_hi(v.x); l[0] = split_lo(v.x);
        h[1] = split_hi(v.y); l[1] = split_lo(v.y);
        h[2] = split_hi(v.z); l[2] = split_lo(v.z);
        h[3] = split_hi(v.w); l[3] = split_lo(v.w);
        *(bf16x4*)(wr + j) = h;
        *(bf16x4*)(wr + 8192 + j) = l;
    }
}

// ------- label softmax + y, 2 rows/block, float4-vectorized ------------------
// logits = S[row][j] - TEMP * sum_c preds[row][c]*M2Tt[c][j]
__global__ __launch_bounds__(256) void k_lab_softmax_y(const float* __restrict__ S,
                                                       const float* __restrict__ predsG,
                                                       const float* __restrict__ M2Tt,
                                                       const float* __restrict__ atlt,
                                                       float* __restrict__ y) {
    int r0 = blockIdx.x * 2, r1 = r0 + 1;
    float pr0[NC], pr1[NC];
    #pragma unroll
    for (int c = 0; c < NC; c++) {
        pr0[c] = predsG[(size_t)r0 * NC + c];
        pr1[c] = predsG[(size_t)r1 * NC + c];
    }
    const float4* s0 = (const float4*)(S + (size_t)r0 * NS);
    const float4* s1 = (const float4*)(S + (size_t)r1 * NS);
    const float4* M2 = (const float4*)M2Tt;    // [NC][2048]
    const float4* AT = (const float4*)atlt;    // [NC][2048]
    float4 v0[NS / 1024], v1[NS / 1024];       // 8 each
    float m0 = -1e30f, m1 = -1e30f;
    #pragma unroll
    for (int u = 0; u < NS / 1024; u++) {
        int j4 = threadIdx.x + u * 256;
        float4 a = s0[j4], b = s1[j4];
        float4 lab0 = make_float4(0.f, 0.f, 0.f, 0.f);
        float4 lab1 = make_float4(0.f, 0.f, 0.f, 0.f);
        #pragma unroll
        for (int c = 0; c < NC; c++) {
            float4 mv = M2[c * 2048 + j4];
            lab0.x += pr0[c] * mv.x; lab0.y += pr0[c] * mv.y;
            lab0.z += pr0[c] * mv.z; lab0.w += pr0[c] * mv.w;
            lab1.x += pr1[c] * mv.x; lab1.y += pr1[c] * mv.y;
            lab1.z += pr1[c] * mv.z; lab1.w += pr1[c] * mv.w;
        }
        a.x -= TEMP * lab0.x; a.y -= TEMP * lab0.y;
        a.z -= TEMP * lab0.z; a.w -= TEMP * lab0.w;
        b.x -= TEMP * lab1.x; b.y -= TEMP * lab1.y;
        b.z -= TEMP * lab1.z; b.w -= TEMP * lab1.w;
        v0[u] = a; v1[u] = b;
        m0 = fmaxf(m0, fmaxf(fmaxf(a.x, a.y), fmaxf(a.z, a.w)));
        m1 = fmaxf(m1, fmaxf(fmaxf(b.x, b.y), fmaxf(b.z, b.w)));
    }
    __shared__ float sm[2][4];
    __shared__ float ss[2][4];
    __shared__ float yred[4][2][NC];
    int lane = threadIdx.x & 63, wid = threadIdx.x >> 6;
    float wm0 = wave_max(m0), wm1 = wave_max(m1);
    if (lane == 0) { sm[0][wid] = wm0; sm[1][wid] = wm1; }
    __syncthreads();
    float bm0 = fmaxf(fmaxf(sm[0][0], sm[0][1]), fmaxf(sm[0][2], sm[0][3]));
    float bm1 = fmaxf(fmaxf(sm[1][0], sm[1][1]), fmaxf(sm[1][2], sm[1][3]));
    float ls0 = 0.f, ls1 = 0.f;
    #pragma unroll
    for (int u = 0; u < NS / 1024; u++) {
        float4 a = v0[u], b = v1[u];
        a.x = __expf(a.x - bm0); a.y = __expf(a.y - bm0);
        a.z = __expf(a.z - bm0); a.w = __expf(a.w - bm0);
        b.x = __expf(b.x - bm1); b.y = __expf(b.y - bm1);
        b.z = __expf(b.z - bm1); b.w = __expf(b.w - bm1);
        v0[u] = a; v1[u] = b;
        ls0 += a.x + a.y + a.z + a.w;
        ls1 += b.x + b.y + b.z + b.w;
    }
    float ws0 = wave_sum(ls0), ws1 = wave_sum(ls1);
    if (lane == 0) { ss[0][wid] = ws0; ss[1][wid] = ws1; }
    __syncthreads();
    float inv0 = 1.0f / (ss[0][0] + ss[0][1] + ss[0][2] + ss[0][3]);
    float inv1 = 1.0f / (ss[1][0] + ss[1][1] + ss[1][2] + ss[1][3]);
    float y0[NC] = {}, y1[NC] = {};
    #pragma unroll
    for (int u = 0; u < NS / 1024; u++) {
        int j4 = threadIdx.x + u * 256;
        float4 a = v0[u], b = v1[u];
        #pragma unroll
        for (int c = 0; c < NC; c++) {
            float4 av = AT[c * 2048 + j4];
            y0[c] += a.x * av.x + a.y * av.y + a.z * av.z + a.w * av.w;
            y1[c] += b.x * av.x + b.y * av.y + b.z * av.z + b.w * av.w;
        }
    }
    #pragma unroll
    for (int c = 0; c < NC; c++) {
        y0[c] = wave_sum(y0[c]) * inv0;
        y1[c] = wave_sum(y1[c]) * inv1;
    }
    if (lane == 0) {
        #pragma unroll
        for (int c = 0; c < NC; c++) { yred[wid][0][c] = y0[c]; yred[wid][1][c] = y1[c]; }
    }
    __syncthreads();
    if (threadIdx.x < 2 * NC) {
        int r = threadIdx.x / NC, c = threadIdx.x - r * NC;
        y[(size_t)(r0 + r) * NC + c] = yred[0][r][c] + yred[1][r][c] + yred[2][r][c] + yred[3][r][c];
    }
}

extern "C" void kernel_launch(void* const* d_in, const int* in_sizes, int n_in,
                              void* d_out, int out_size, void* d_ws, size_t ws_size,
                              hipStream_t stream) {
    const float* x    = (const float*)d_in[0];   // [1024, 32, 32]
    const float* tf   = (const float*)d_in[1];   // [8192, 1024]
    const float* asf  = (const float*)d_in[2];   // [8192, 1024]
    const float* sf   = (const float*)d_in[3];   // [8192, 1024]
    const float* shdl = (const float*)d_in[4];   // [8192, 10]
    const float* atl  = (const float*)d_in[5];   // [8192, 10]
    const float* sld  = (const float*)d_in[6];   // [10, 10]
    const float* W    = (const float*)d_in[7];   // [1024, 10]
    const float* bias = (const float*)d_in[8];   // [10]
    float* y = (float*)d_out;                    // [1024, 10]

    char* wsb = (char*)d_ws;
    // Region lifetimes:
    //  R0 @0   (32 MiB): S (G1 logits) -> asfT2 (after softmax_w2) -> S (G3 logits)
    //  R1 @32  (32 MiB): tf2 (until G1) -> parts (G2 out, until k_fuse2)
    //  R2 @64  (32 MiB): w2 (until G2) -> sf2 (written by k_fuse2, read by G3)
    float*  S     = (float*)(wsb);
    __bf16* asfT2 = (__bf16*)S;
    float*  BIG1  = (float*)(wsb + (32u << 20));
    __bf16* tf2   = (__bf16*)BIG1;
    float*  parts = BIG1;
    __bf16* w2    = (__bf16*)(wsb + (64u << 20));
    __bf16* sf2   = (__bf16*)(wsb + (64u << 20));
    __bf16* x2    = (__bf16*)(wsb + (96u << 20));           // 4 MiB
    __bf16* xsrc2 = (__bf16*)(wsb + (100u << 20));          // 4 MiB
    float*  nt_   = (float*)(wsb + (108u << 20));
    float*  ns_   = nt_ + NT;
    float*  nx_   = ns_ + NS;
    float*  nx2_  = nx_ + B_ROWS;
    float*  preds = nx2_ + B_ROWS;
    float*  M2Tt  = preds + B_ROWS * NC;                    // [10][8192]
    float*  atlt  = M2Tt + NS * NC;                         // [10][8192]

    // K0: conv_norm(x) + conv_norm(tf) + prep_labels
    k_prep0<<<B_ROWS + NT + NS / 256, 256, 0, stream>>>(x, tf, sld, shdl, atl,
                                                        x2, tf2, nx_, nt_, M2Tt, atlt);

    // G1: S = logits(-TEMP*d(x, tf))   (M=1024, N=8192, K=1024)
    {
        dim3 g(NT / 128, B_ROWS / 128, 1);
        k_gemm3<true><<<g, 256, 0, stream>>>(x2, tf2, S, B_ROWS, NT, DIM, DIM,
                                             nx_, nt_);
    }
    // w_feat softmax -> split-bf16 w2 (vectorized)
    k_softmax_w2<<<B_ROWS, 256, 0, stream>>>(S, w2);
    // conv2t(asf) into R0 (S dead after softmax)
    k_conv2t<<<2048, 256, 0, stream>>>(asf, asfT2);
    // G2: parts[z] = w2 @ asfT2^T  (M=1024, N=1024, K=8192, split-K x8) -> R1
    {
        dim3 g(DIM / 128, B_ROWS / 128, 8);
        k_gemm3<false><<<g, 256, 0, stream>>>(w2, asfT2, parts, B_ROWS, DIM, NT, NT / 8,
                                              nullptr, nullptr);
    }
    // K_fuse2: reduce8+split+norm+preds (reads R1) AND conv_norm(sf) -> R2 (w2 dead)
    k_fuse2<<<B_ROWS + NS, 256, 0, stream>>>(parts, sf, W, bias, xsrc2, sf2,
                                             nx2_, ns_, preds);

    // G3: S = logits(-TEMP*d(xsrc, sf))  (M=1024, N=8192, K=1024) -> R0
    {
        dim3 g(NS / 128, B_ROWS / 128, 1);
        k_gemm3<true><<<g, 256, 0, stream>>>(xsrc2, sf2, S, B_ROWS, NS, DIM, DIM,
                                             nx2_, ns_);
    }
    // label softmax (with M2T term) + y, 2 rows/block (vectorized)
    k_lab_softmax_y<<<B_ROWS / 2, 256, 0, stream>>>(S, preds, M2Tt, atlt, y);
}